// Round 17
// baseline (1140.426 us; speedup 1.0000x reference)
//
#include <hip/hip_runtime.h>
#include <hip/hip_bf16.h>
#include <math.h>

#define NODE 90
#define HID 256
#define NB 512
#define NN (NB * 90)
#define EDGES (NB * 2700)
#define XLD 96

typedef __attribute__((ext_vector_type(8))) short bf16x8;
typedef __attribute__((ext_vector_type(4))) float f32x4;

__device__ __forceinline__ float tanh_safe(float s) {
    s = fminf(fmaxf(s, -15.f), 15.f);
    float t = __expf(2.f * s);
    return (t - 1.f) / (t + 1.f);
}
__device__ __forceinline__ unsigned short f2b(float x) {
    unsigned u = __float_as_uint(x);
    return (unsigned short)((u + 0x7FFFu + ((u >> 16) & 1u)) >> 16);
}
__device__ __forceinline__ float b2f(unsigned short h) {
    return __uint_as_float(((unsigned)h) << 16);
}

// ---------------------------------------------------------------------------
__device__ float g_adjS[(size_t)NB * NODE * NODE];
__device__ float g_adjF[(size_t)NB * NODE * NODE];
__device__ float g_T[(size_t)2 * NN * HID];
__device__ float g_P[(size_t)NB * NODE * NODE];
__device__ float g_fn[NB * 96];
__device__ float g_gm[NB * 96];

__device__ unsigned short g_hshi[(size_t)NN * HID], g_hslo[(size_t)NN * HID];
__device__ unsigned short g_hfhi[(size_t)NN * HID], g_hflo[(size_t)NN * HID];
__device__ unsigned short g_cshi[(size_t)NN * HID], g_cslo[(size_t)NN * HID];
__device__ unsigned short g_cfhi[(size_t)NN * HID], g_cflo[(size_t)NN * HID];
__device__ unsigned short g_xshi[(size_t)NN * XLD], g_xslo[(size_t)NN * XLD];
__device__ unsigned short g_xfhi[(size_t)NN * XLD], g_xflo[(size_t)NN * XLD];
__device__ unsigned short g_t2hi[(size_t)NN * HID], g_t2lo[(size_t)NN * HID];
__device__ unsigned short g_w0thi[256 * XLD], g_w0tlo[256 * XLD];
__device__ unsigned short g_wathi[256 * 256], g_watlo[256 * 256];
__device__ unsigned short g_w1thi[256 * 512], g_w1tlo[256 * 512];

__device__ __forceinline__ float* adjPtr(int w) { return w ? g_adjF : g_adjS; }
__device__ __forceinline__ unsigned short* selhi(int w) {
    switch (w) {
        case 0: return g_hshi;
        case 1: return g_hfhi;
        case 2: return g_cshi;
        case 3: return g_cfhi;
        case 4: return g_xshi;
        default: return g_xfhi;
    }
}
__device__ __forceinline__ unsigned short* sello(int w) {
    switch (w) {
        case 0: return g_hslo;
        case 1: return g_hflo;
        case 2: return g_cslo;
        case 3: return g_cflo;
        case 4: return g_xslo;
        default: return g_xflo;
    }
}
__device__ __forceinline__ unsigned short* wthi(int w) {
    switch (w) { case 0: return g_w0thi; case 1: return g_wathi; default: return g_w1thi; }
}
__device__ __forceinline__ unsigned short* wtlo(int w) {
    switch (w) { case 0: return g_w0tlo; case 1: return g_watlo; default: return g_w1tlo; }
}

// ---------------------------------------------------------------------------
// Fused adjacency with block-local dtype detection (deterministic).
// ---------------------------------------------------------------------------
__global__ __launch_bounds__(256) void k_adj_fused(const void* __restrict__ eS,
                                                   const void* __restrict__ eF) {
    __shared__ float cnt[NODE][NODE + 1];
    __shared__ float dinv[NODE];
    __shared__ int s_e64;
    int side = blockIdx.x >> 9;
    int b = blockIdx.x & 511;
    const void* edges = side ? eF : eS;
    int tid = threadIdx.x;
    const int* p32 = (const int*)edges;
    if (tid == 0) s_e64 = 1;
    for (int i = tid; i < NODE * (NODE + 1); i += 256) (&cnt[0][0])[i] = 0.f;
    __syncthreads();
    // int64 edges < 2^31 have zero high (odd) words; int32 data has mostly
    // nonzero odd words (edge endpoints). Benign same-value LDS race.
    for (int i = tid; i < 1024; i += 256)
        if (p32[2 * i + 1] != 0) s_e64 = 0;
    __syncthreads();
    int e64 = s_e64;
    const long long* p64 = (const long long*)edges;
    for (int i = tid; i < 2700; i += 256) {
        int idx = b * 2700 + i;
        long long s, d;
        if (e64) { s = p64[idx]; d = p64[EDGES + idx]; }
        else     { s = p32[idx]; d = p32[EDGES + idx]; }
        int sl = (int)s - b * NODE, dl = (int)d - b * NODE;
        if (sl >= 0 && sl < NODE && dl >= 0 && dl < NODE)
            atomicAdd(&cnt[dl][sl], 1.0f);
    }
    __syncthreads();
    if (tid < NODE) {
        float s = 0.f;
        for (int k = 0; k < NODE; k++) s += cnt[tid][k];
        dinv[tid] = (s > 0.f) ? rsqrtf(s) : 0.f;
    }
    __syncthreads();
    float* adj = adjPtr(side) + (size_t)b * NODE * NODE;
    for (int i = tid; i < NODE * NODE; i += 256) {
        int d = i / NODE, s = i - d * NODE;
        adj[i] = cnt[d][s] * dinv[d] * dinv[s];
    }
}

// ---------------------------------------------------------------------------
// All input conversions in ONE dispatch.
//   blocks [0,2160): x_sc -> planes ; [2160,4320): x_fc
//   [4320,4332): W0 ; [4332,4364): Wa ; [4364,4428): W1 (transposed planes)
// ---------------------------------------------------------------------------
__global__ void k_conv_all(const float* __restrict__ xs, const float* __restrict__ xf,
                           const float* __restrict__ W0, const float* __restrict__ Wa,
                           const float* __restrict__ W1) {
    int gid = blockIdx.x;
    int tid = threadIdx.x;
    if (gid < 4320) {
        int side = (gid >= 2160);
        int t = (gid - side * 2160) * 256 + tid;      // < NN*12 exactly
        const float* X = side ? xf : xs;
        int r = t / 12, o = t - r * 12;
        unsigned short h8[8], l8[8];
#pragma unroll
        for (int j = 0; j < 8; j++) {
            int k = 8 * o + j;
            float x = (k < NODE) ? X[(size_t)r * NODE + k] : 0.f;
            unsigned short h = f2b(x);
            h8[j] = h;
            l8[j] = f2b(x - b2f(h));
        }
        unsigned short* ph = side ? g_xfhi : g_xshi;
        unsigned short* pl = side ? g_xflo : g_xslo;
        *(uint4*)&ph[(size_t)r * XLD + 8 * o] = *(uint4*)h8;
        *(uint4*)&pl[(size_t)r * XLD + 8 * o] = *(uint4*)l8;
    } else {
        const float* W;
        int K, Kpad, which, t;
        if (gid < 4332)      { W = W0; K = NODE; Kpad = XLD; which = 0; t = (gid - 4320) * 256 + tid; }
        else if (gid < 4364) { W = Wa; K = 256;  Kpad = 256; which = 1; t = (gid - 4332) * 256 + tid; }
        else                 { W = W1; K = 512;  Kpad = 512; which = 2; t = (gid - 4364) * 256 + tid; }
        int c = t / (Kpad / 8), o = t - c * (Kpad / 8);
        unsigned short h8[8], l8[8];
#pragma unroll
        for (int j = 0; j < 8; j++) {
            int k = 8 * o + j;
            float x = (k < K) ? W[(size_t)k * 256 + c] : 0.f;
            unsigned short h = f2b(x);
            h8[j] = h;
            l8[j] = f2b(x - b2f(h));
        }
        *(uint4*)&wthi(which)[(size_t)c * Kpad + 8 * o] = *(uint4*)h8;
        *(uint4*)&wtlo(which)[(size_t)c * Kpad + 8 * o] = *(uint4*)l8;
    }
}

// ---------------------------------------------------------------------------
// Two-sided MFMA bf16x2-split GEMM. Blocks [0,nSide) = side S (xsA/x2sA,
// rows 0..NN of g_T); [nSide,2*nSide) = side F (xsB/x2sB, rows NN..2NN).
// emitT2=1: write hi/lo planes to g_t2* instead of fp32 g_T.
// ---------------------------------------------------------------------------
#define GK 32
#define ASTR 40
__global__ __launch_bounds__(256) void k_gemm_mfma(int xsA, int x2sA, int xsB, int x2sB,
                                                   int kld, int K, int wsel, int wld,
                                                   int emitT2, int nSide) {
    __shared__ unsigned short Ah[64][ASTR], Al[64][ASTR];
    __shared__ unsigned short Bh[64][ASTR], Bl[64][ASTR];
    int tid = threadIdx.x;
    int id = blockIdx.x;
    int side = (id >= nSide);
    int idL = side ? id - nSide : id;
    int bn = idL & 3, bm = idL >> 2;
    int r0 = bm * 64, c0 = bn * 64;
    int tbase = side ? NN : 0;
    int xsel = side ? xsB : xsA;
    int x2sel = side ? x2sB : x2sA;
    const unsigned short* whi_ = wthi(wsel);
    const unsigned short* wlo_ = wtlo(wsel);

    int w = tid >> 6;
    int l = tid & 63;
    int lr = l & 15;
    int lq = l >> 4;
    int koff = lq * 8;
    int sr = tid >> 2, so = (tid & 3) * 8;

    f32x4 acc[4];
#pragma unroll
    for (int c = 0; c < 4; c++) acc[c] = (f32x4){0.f, 0.f, 0.f, 0.f};

    int nt = K / GK;
    for (int t = 0; t < nt; t++) {
        int k0 = t * GK;
        const unsigned short *phi, *plo;
        int xc;
        if (x2sel >= 0 && k0 >= HID) { phi = selhi(x2sel); plo = sello(x2sel); xc = k0 - HID; }
        else                          { phi = selhi(xsel);  plo = sello(xsel);  xc = k0; }

        __syncthreads();
        {
            size_t ga = (size_t)(r0 + sr) * kld + xc + so;
            *(uint4*)&Ah[sr][so] = *(const uint4*)&phi[ga];
            *(uint4*)&Al[sr][so] = *(const uint4*)&plo[ga];
            size_t gb = (size_t)(c0 + sr) * wld + k0 + so;
            *(uint4*)&Bh[sr][so] = *(const uint4*)&whi_[gb];
            *(uint4*)&Bl[sr][so] = *(const uint4*)&wlo_[gb];
        }
        __syncthreads();

        bf16x8 ah = *(const bf16x8*)&Ah[16 * w + lr][koff];
        bf16x8 al = *(const bf16x8*)&Al[16 * w + lr][koff];
#pragma unroll
        for (int c = 0; c < 4; c++) {
            bf16x8 bh = *(const bf16x8*)&Bh[16 * c + lr][koff];
            bf16x8 bl = *(const bf16x8*)&Bl[16 * c + lr][koff];
            acc[c] = __builtin_amdgcn_mfma_f32_16x16x32_bf16(ah, bh, acc[c], 0, 0, 0);
            acc[c] = __builtin_amdgcn_mfma_f32_16x16x32_bf16(ah, bl, acc[c], 0, 0, 0);
            acc[c] = __builtin_amdgcn_mfma_f32_16x16x32_bf16(al, bh, acc[c], 0, 0, 0);
        }
    }

#pragma unroll
    for (int c = 0; c < 4; c++) {
#pragma unroll
        for (int qq = 0; qq < 4; qq++) {
            size_t row = (size_t)(tbase + r0 + 16 * w + 4 * lq + qq);
            size_t col = c0 + 16 * c + lr;
            float v = acc[c][qq];
            if (emitT2) {
                unsigned short h = f2b(v);
                g_t2hi[row * HID + col] = h;
                g_t2lo[row * HID + col] = f2b(v - b2f(h));
            } else {
                g_T[row * HID + col] = v;
            }
        }
    }
}

// ---------------------------------------------------------------------------
// Fused two-stream aggregate; emits h planes + d_out copy (NO fp32 h).
// ---------------------------------------------------------------------------
__global__ __launch_bounds__(256) void k_agg2(const float* __restrict__ bias,
                                              float* __restrict__ outS,
                                              float* __restrict__ outF) {
    __shared__ float AdjT[NODE][102];
    int tid = threadIdx.x;
    int idx = blockIdx.x;
    int side = idx >> 10;
    int b = (idx & 1023) >> 1;
    int c0 = (idx & 1) * 128;
    const float* Adj = adjPtr(side) + (size_t)b * NODE * NODE;
    const float* Tg = g_T + ((size_t)side * NN + (size_t)b * NODE) * HID;
    float* outp = side ? outF : outS;
    unsigned short* phD = selhi(side);
    unsigned short* plD = sello(side);

    for (int i = tid; i < NODE * NODE; i += 256) {
        int n = i / NODE, k = i - n * NODE;
        AdjT[k][n] = Adj[i];
    }
    for (int i = tid; i < NODE * 12; i += 256) {
        int k = i / 12, n = NODE + (i % 12);
        AdjT[k][n] = 0.f;
    }
    __syncthreads();

    int ti = tid & 15, tj = tid >> 4;
    int rbase = 6 * ti;
    int cc = c0 + 8 * tj;

    float acc[6][8];
#pragma unroll
    for (int i = 0; i < 6; i++)
#pragma unroll
        for (int j = 0; j < 8; j++) acc[i][j] = 0.f;

#pragma unroll 2
    for (int k = 0; k < NODE; k++) {
        float4 t0 = *(const float4*)&Tg[(size_t)k * HID + cc];
        float4 t1 = *(const float4*)&Tg[(size_t)k * HID + cc + 4];
        float bv[8] = {t0.x, t0.y, t0.z, t0.w, t1.x, t1.y, t1.z, t1.w};
        float2 a01 = *(const float2*)&AdjT[k][rbase];
        float2 a23 = *(const float2*)&AdjT[k][rbase + 2];
        float2 a45 = *(const float2*)&AdjT[k][rbase + 4];
        float av[6] = {a01.x, a01.y, a23.x, a23.y, a45.x, a45.y};
#pragma unroll
        for (int i = 0; i < 6; i++)
#pragma unroll
            for (int j = 0; j < 8; j++)
                acc[i][j] = fmaf(av[i], bv[j], acc[i][j]);
    }

    float bb[8];
#pragma unroll
    for (int j = 0; j < 8; j++) bb[j] = bias[cc + j];

#pragma unroll
    for (int i = 0; i < 6; i++) {
        int n = rbase + i;
        if (n < NODE) {
            size_t row = (size_t)(b * NODE + n);
            float v[8];
            unsigned short h8[8], l8[8];
#pragma unroll
            for (int j = 0; j < 8; j++) {
                v[j] = fmaxf(acc[i][j] + bb[j], 0.f);
                unsigned short h = f2b(v[j]);
                h8[j] = h;
                l8[j] = f2b(v[j] - b2f(h));
            }
            *(float4*)&outp[row * 512 + cc] = make_float4(v[0], v[1], v[2], v[3]);
            *(float4*)&outp[row * 512 + cc + 4] = make_float4(v[4], v[5], v[6], v[7]);
            *(uint4*)&phD[row * HID + cc] = *(uint4*)h8;
            *(uint4*)&plD[row * HID + cc] = *(uint4*)l8;
        }
    }
}

// ---------------------------------------------------------------------------
// Scores via MFMA (col<92 guard). P = row-softmax -> g_P; fn/gm vectors.
// ---------------------------------------------------------------------------
__global__ __launch_bounds__(256) void k_score_mfma(int hfsel) {
    __shared__ unsigned short Ah[96][ASTR], Al[96][ASTR];
    __shared__ unsigned short Bh[96][ASTR], Bl[96][ASTR];
    __shared__ float Pm[96][92];
    __shared__ float rmax_[96], rinv_[96], fn_[96], gm_[96];

    int b = blockIdx.x;
    int tid = threadIdx.x;
    const unsigned short* t2h = g_t2hi + (size_t)b * NODE * HID;
    const unsigned short* t2l = g_t2lo + (size_t)b * NODE * HID;
    const unsigned short* hfh = selhi(hfsel) + (size_t)b * NODE * HID;
    const unsigned short* hfl_ = sello(hfsel) + (size_t)b * NODE * HID;

    int w = tid >> 6, l = tid & 63;
    int lr = l & 15, lq = l >> 4, koff = 8 * lq;
    int wr = w >> 1, wc = w & 1;

    f32x4 acc[3][3];
#pragma unroll
    for (int i = 0; i < 3; i++)
#pragma unroll
        for (int j = 0; j < 3; j++) acc[i][j] = (f32x4){0.f, 0.f, 0.f, 0.f};

    const uint4 z4 = make_uint4(0, 0, 0, 0);
    for (int t = 0; t < 8; t++) {
        int k0 = 32 * t;
        __syncthreads();
        for (int i = tid; i < 96 * 4; i += 256) {
            int r = i >> 2, o = (i & 3) << 3;
            uint4 vah = z4, val = z4, vbh = z4, vbl = z4;
            if (r < NODE) {
                size_t g = (size_t)r * HID + k0 + o;
                vah = *(const uint4*)&t2h[g];
                val = *(const uint4*)&t2l[g];
                vbh = *(const uint4*)&hfh[g];
                vbl = *(const uint4*)&hfl_[g];
            }
            *(uint4*)&Ah[r][o] = vah;
            *(uint4*)&Al[r][o] = val;
            *(uint4*)&Bh[r][o] = vbh;
            *(uint4*)&Bl[r][o] = vbl;
        }
        __syncthreads();

        bf16x8 ah[3], al[3], bh[3], bl[3];
#pragma unroll
        for (int i = 0; i < 3; i++) {
            ah[i] = *(const bf16x8*)&Ah[48 * wr + 16 * i + lr][koff];
            al[i] = *(const bf16x8*)&Al[48 * wr + 16 * i + lr][koff];
            bh[i] = *(const bf16x8*)&Bh[48 * wc + 16 * i + lr][koff];
            bl[i] = *(const bf16x8*)&Bl[48 * wc + 16 * i + lr][koff];
        }
#pragma unroll
        for (int i = 0; i < 3; i++)
#pragma unroll
            for (int j = 0; j < 3; j++) {
                acc[i][j] = __builtin_amdgcn_mfma_f32_16x16x32_bf16(ah[i], bh[j], acc[i][j], 0, 0, 0);
                acc[i][j] = __builtin_amdgcn_mfma_f32_16x16x32_bf16(ah[i], bl[j], acc[i][j], 0, 0, 0);
                acc[i][j] = __builtin_amdgcn_mfma_f32_16x16x32_bf16(al[i], bh[j], acc[i][j], 0, 0, 0);
            }
    }

#pragma unroll
    for (int i = 0; i < 3; i++)
#pragma unroll
        for (int j = 0; j < 3; j++)
#pragma unroll
            for (int qq = 0; qq < 4; qq++) {
                int row = 48 * wr + 16 * i + 4 * lq + qq;
                int col = 48 * wc + 16 * j + lr;
                if (col < 92)
                    Pm[row][col] = tanh_safe(acc[i][j][qq]);
            }
    __syncthreads();

    if (tid < NODE) {
        int n = tid;
        float mx = -2.f;
        for (int m = 0; m < NODE; m++) mx = fmaxf(mx, Pm[n][m]);
        float s = 0.f;
        for (int m = 0; m < NODE; m++) s += __expf(Pm[n][m] - mx);
        rmax_[n] = mx;
        rinv_[n] = 1.f / s;
        fn_[n] = s * __expf(mx);
    } else if (tid >= 128 && tid < 128 + NODE) {
        int m = tid - 128;
        float mx = -2.f;
        for (int n = 0; n < NODE; n++) mx = fmaxf(mx, Pm[n][m]);
        float s = 0.f;
        for (int n = 0; n < NODE; n++) s += __expf(Pm[n][m] - mx);
        gm_[m] = __expf(-mx) / s;
    }
    __syncthreads();

    float* Pg = g_P + (size_t)b * NODE * NODE;
    for (int i = tid; i < NODE * NODE; i += 256) {
        int n = i / NODE, m = i - n * NODE;
        Pg[i] = __expf(Pm[n][m] - rmax_[n]) * rinv_[n];
    }
    if (tid < NODE) {
        g_fn[b * 96 + tid] = fn_[tid];
        g_gm[b * 96 + tid] = gm_[tid];
    }
}

// ---------------------------------------------------------------------------
// Merged PV: blocks [0,1024) = co_s (P @ HF), [1024,2048) = co_f
// (gm[m] * sum_n P[n][m]*fn[n] * HS[n]). H read from hi+lo planes (fp32-exact).
// ---------------------------------------------------------------------------
__global__ __launch_bounds__(256) void k_pv(int fsel, int ssel, int cssel, int cfsel,
                                            float* __restrict__ outS,
                                            float* __restrict__ outF, int emit) {
    __shared__ float Pl[NODE][91];
    __shared__ float Hl[NODE][129];
    __shared__ float fnl[96], gml[96];
    int id = blockIdx.x;
    int isPV3 = (id >= 1024);
    int idL = isPV3 ? id - 1024 : id;
    int b = idL >> 1;
    int c0 = (idL & 1) * 128;
    int tid = threadIdx.x;

    const float* Pg = g_P + (size_t)b * NODE * NODE;
    for (int i = tid; i < NODE * NODE; i += 256) {
        int n = i / NODE, m = i - n * NODE;
        Pl[n][m] = Pg[i];
    }
    {
        int hsel = isPV3 ? ssel : fsel;
        const unsigned short* Hh = selhi(hsel) + (size_t)b * NODE * HID;
        const unsigned short* Hlo = sello(hsel) + (size_t)b * NODE * HID;
        for (int i = tid; i < NODE * 16; i += 256) {
            int r = i >> 4, o = (i & 15) << 3;
            uint4 vh = *(const uint4*)&Hh[(size_t)r * HID + c0 + o];
            uint4 vl = *(const uint4*)&Hlo[(size_t)r * HID + c0 + o];
            const unsigned short* ph = (const unsigned short*)&vh;
            const unsigned short* pl = (const unsigned short*)&vl;
#pragma unroll
            for (int j = 0; j < 8; j++)
                Hl[r][o + j] = b2f(ph[j]) + b2f(pl[j]);
        }
    }
    if (isPV3 && tid < 96) {
        fnl[tid] = (tid < NODE) ? g_fn[b * 96 + tid] : 0.f;
        gml[tid] = (tid < NODE) ? g_gm[b * 96 + tid] : 0.f;
    }
    __syncthreads();

    int c4 = (tid & 31) << 2;
    int rg = tid >> 5;
    float acc[12][4];
#pragma unroll
    for (int k = 0; k < 12; k++)
#pragma unroll
        for (int j = 0; j < 4; j++) acc[k][j] = 0.f;

    if (!isPV3) {
#pragma unroll 2
        for (int m = 0; m < NODE; m++) {
            float4 h = *(const float4*)&Hl[m][c4];
#pragma unroll
            for (int k = 0; k < 12; k++) {
                int n = rg + 8 * k;
                float p = Pl[(n < NODE) ? n : 0][m];
                acc[k][0] = fmaf(p, h.x, acc[k][0]);
                acc[k][1] = fmaf(p, h.y, acc[k][1]);
                acc[k][2] = fmaf(p, h.z, acc[k][2]);
                acc[k][3] = fmaf(p, h.w, acc[k][3]);
            }
        }
        unsigned short* csh = selhi(cssel);
        unsigned short* csl = sello(cssel);
#pragma unroll
        for (int k = 0; k < 12; k++) {
            int n = rg + 8 * k;
            if (n < NODE) {
                size_t row = (size_t)(b * NODE + n);
                size_t gc = c0 + c4;
                *(float4*)&outS[row * 512 + gc] =
                    make_float4(acc[k][0], acc[k][1], acc[k][2], acc[k][3]);
                if (emit) {
                    unsigned short h4[4], l4[4];
#pragma unroll
                    for (int j = 0; j < 4; j++) {
                        unsigned short h = f2b(acc[k][j]);
                        h4[j] = h;
                        l4[j] = f2b(acc[k][j] - b2f(h));
                    }
                    *(uint2*)&csh[row * HID + gc] = *(uint2*)h4;
                    *(uint2*)&csl[row * HID + gc] = *(uint2*)l4;
                }
            }
        }
    } else {
#pragma unroll 2
        for (int n = 0; n < NODE; n++) {
            float4 h = *(const float4*)&Hl[n][c4];
            float f = fnl[n];
#pragma unroll
            for (int k = 0; k < 12; k++) {
                int m = rg + 8 * k;
                float p = Pl[n][(m < NODE) ? m : 0] * f;
                acc[k][0] = fmaf(p, h.x, acc[k][0]);
                acc[k][1] = fmaf(p, h.y, acc[k][1]);
                acc[k][2] = fmaf(p, h.z, acc[k][2]);
                acc[k][3] = fmaf(p, h.w, acc[k][3]);
            }
        }
        unsigned short* cfh = selhi(cfsel);
        unsigned short* cfl = sello(cfsel);
#pragma unroll
        for (int k = 0; k < 12; k++) {
            int m = rg + 8 * k;
            if (m < NODE) {
                float g = gml[m];
                size_t row = (size_t)(b * NODE + m);
                size_t gc = c0 + c4;
                float o4[4] = {acc[k][0] * g, acc[k][1] * g, acc[k][2] * g, acc[k][3] * g};
                *(float4*)&outF[row * 512 + gc] = make_float4(o4[0], o4[1], o4[2], o4[3]);
                if (emit) {
                    unsigned short h4[4], l4[4];
#pragma unroll
                    for (int j = 0; j < 4; j++) {
                        unsigned short h = f2b(o4[j]);
                        h4[j] = h;
                        l4[j] = f2b(o4[j] - b2f(h));
                    }
                    *(uint2*)&cfh[row * HID + gc] = *(uint2*)h4;
                    *(uint2*)&cfl[row * HID + gc] = *(uint2*)l4;
                }
            }
        }
    }
}

// ---------------------------------------------------------------------------
extern "C" void kernel_launch(void* const* d_in, const int* in_sizes, int n_in,
                              void* d_out, int out_size, void* d_ws, size_t ws_size,
                              hipStream_t stream) {
    const float* x_sc = (const float*)d_in[0];
    const void* e_sc = d_in[1];
    const float* x_fc = (const float*)d_in[2];
    const void* e_fc = d_in[3];
    const float* W0 = (const float*)d_in[4];
    const float* b0 = (const float*)d_in[5];
    const float* W1 = (const float*)d_in[6];
    const float* b1 = (const float*)d_in[7];
    const float* Wa = (const float*)d_in[8];

    float* out = (float*)d_out;
    size_t os = (size_t)NN * 512;
    float* x1s = out;
    float* x2s = out + os;
    float* x1f = out + 2 * os;
    float* x2f = out + 3 * os;

    const int NS = (NN / 64) * 4;    // 2880 blocks per side

    k_adj_fused<<<1024, 256, 0, stream>>>(e_sc, e_fc);
    k_conv_all<<<4428, 256, 0, stream>>>(x_sc, x_fc, W0, Wa, W1);

    // ---- layer 1 (both sides in one dispatch) ----
    k_gemm_mfma<<<2 * NS, 256, 0, stream>>>(4, -1, 5, -1, XLD, XLD, 0, XLD, 0, NS);
    k_agg2<<<2048, 256, 0, stream>>>(b0, x1s, x1f);

    // ---- co-attention 1 ----
    k_gemm_mfma<<<NS, 256, 0, stream>>>(0, -1, 0, -1, HID, 256, 1, 256, 1, NS);
    k_score_mfma<<<NB, 256, 0, stream>>>(1);
    k_pv<<<2048, 256, 0, stream>>>(1, 0, 2, 3, x1s + HID, x1f + HID, 1);

    // ---- layer 2 (both sides) ----
    k_gemm_mfma<<<2 * NS, 256, 0, stream>>>(0, 2, 1, 3, HID, 512, 2, 512, 0, NS);
    k_agg2<<<2048, 256, 0, stream>>>(b1, x2s, x2f);

    // ---- co-attention 2 ----
    k_gemm_mfma<<<NS, 256, 0, stream>>>(0, -1, 0, -1, HID, 256, 1, 256, 1, NS);
    k_score_mfma<<<NB, 256, 0, stream>>>(1);
    k_pv<<<2048, 256, 0, stream>>>(1, 0, 2, 3, x2s + HID, x2f + HID, 0);
}

// Round 18
// 838.423 us; speedup vs baseline: 1.3602x; 1.3602x over previous
//
#include <hip/hip_runtime.h>
#include <hip/hip_bf16.h>
#include <math.h>

#define NODE 90
#define HID 256
#define NB 512
#define NN (NB * 90)
#define EDGES (NB * 2700)
#define XLD 96

typedef __attribute__((ext_vector_type(8))) short bf16x8;
typedef __attribute__((ext_vector_type(4))) float f32x4;

__device__ __forceinline__ float tanh_safe(float s) {
    s = fminf(fmaxf(s, -15.f), 15.f);
    float t = __expf(2.f * s);
    return (t - 1.f) / (t + 1.f);
}
__device__ __forceinline__ unsigned short f2b(float x) {
    unsigned u = __float_as_uint(x);
    return (unsigned short)((u + 0x7FFFu + ((u >> 16) & 1u)) >> 16);
}
__device__ __forceinline__ float b2f(unsigned short h) {
    return __uint_as_float(((unsigned)h) << 16);
}

// ---------------------------------------------------------------------------
__device__ float g_adjS[(size_t)NB * NODE * NODE];
__device__ float g_adjF[(size_t)NB * NODE * NODE];
__device__ float g_T[(size_t)2 * NN * HID];
__device__ float g_P[(size_t)NB * NODE * NODE];
__device__ float g_fn[NB * 96];
__device__ float g_gm[NB * 96];

__device__ unsigned short g_hshi[(size_t)NN * HID], g_hslo[(size_t)NN * HID];
__device__ unsigned short g_hfhi[(size_t)NN * HID], g_hflo[(size_t)NN * HID];
__device__ unsigned short g_cshi[(size_t)NN * HID], g_cslo[(size_t)NN * HID];
__device__ unsigned short g_cfhi[(size_t)NN * HID], g_cflo[(size_t)NN * HID];
__device__ unsigned short g_xshi[(size_t)NN * XLD], g_xslo[(size_t)NN * XLD];
__device__ unsigned short g_xfhi[(size_t)NN * XLD], g_xflo[(size_t)NN * XLD];
__device__ unsigned short g_t2hi[(size_t)NN * HID], g_t2lo[(size_t)NN * HID];
__device__ unsigned short g_w0thi[256 * XLD], g_w0tlo[256 * XLD];
__device__ unsigned short g_wathi[256 * 256], g_watlo[256 * 256];
__device__ unsigned short g_w1thi[256 * 512], g_w1tlo[256 * 512];

__device__ __forceinline__ float* adjPtr(int w) { return w ? g_adjF : g_adjS; }
__device__ __forceinline__ unsigned short* selhi(int w) {
    switch (w) {
        case 0: return g_hshi;
        case 1: return g_hfhi;
        case 2: return g_cshi;
        case 3: return g_cfhi;
        case 4: return g_xshi;
        default: return g_xfhi;
    }
}
__device__ __forceinline__ unsigned short* sello(int w) {
    switch (w) {
        case 0: return g_hslo;
        case 1: return g_hflo;
        case 2: return g_cslo;
        case 3: return g_cflo;
        case 4: return g_xslo;
        default: return g_xflo;
    }
}
__device__ __forceinline__ unsigned short* wthi(int w) {
    switch (w) { case 0: return g_w0thi; case 1: return g_wathi; default: return g_w1thi; }
}
__device__ __forceinline__ unsigned short* wtlo(int w) {
    switch (w) { case 0: return g_w0tlo; case 1: return g_watlo; default: return g_w1tlo; }
}

// ---------------------------------------------------------------------------
// Fused adjacency with block-local dtype detection (deterministic).
// ---------------------------------------------------------------------------
__global__ __launch_bounds__(256) void k_adj_fused(const void* __restrict__ eS,
                                                   const void* __restrict__ eF) {
    __shared__ float cnt[NODE][NODE + 1];
    __shared__ float dinv[NODE];
    __shared__ int s_e64;
    int side = blockIdx.x >> 9;
    int b = blockIdx.x & 511;
    const void* edges = side ? eF : eS;
    int tid = threadIdx.x;
    const int* p32 = (const int*)edges;
    if (tid == 0) s_e64 = 1;
    for (int i = tid; i < NODE * (NODE + 1); i += 256) (&cnt[0][0])[i] = 0.f;
    __syncthreads();
    for (int i = tid; i < 1024; i += 256)
        if (p32[2 * i + 1] != 0) s_e64 = 0;
    __syncthreads();
    int e64 = s_e64;
    const long long* p64 = (const long long*)edges;
    for (int i = tid; i < 2700; i += 256) {
        int idx = b * 2700 + i;
        long long s, d;
        if (e64) { s = p64[idx]; d = p64[EDGES + idx]; }
        else     { s = p32[idx]; d = p32[EDGES + idx]; }
        int sl = (int)s - b * NODE, dl = (int)d - b * NODE;
        if (sl >= 0 && sl < NODE && dl >= 0 && dl < NODE)
            atomicAdd(&cnt[dl][sl], 1.0f);
    }
    __syncthreads();
    if (tid < NODE) {
        float s = 0.f;
        for (int k = 0; k < NODE; k++) s += cnt[tid][k];
        dinv[tid] = (s > 0.f) ? rsqrtf(s) : 0.f;
    }
    __syncthreads();
    float* adj = adjPtr(side) + (size_t)b * NODE * NODE;
    for (int i = tid; i < NODE * NODE; i += 256) {
        int d = i / NODE, s = i - d * NODE;
        adj[i] = cnt[d][s] * dinv[d] * dinv[s];
    }
}

// ---------------------------------------------------------------------------
// All input conversions in ONE dispatch.
// ---------------------------------------------------------------------------
__global__ void k_conv_all(const float* __restrict__ xs, const float* __restrict__ xf,
                           const float* __restrict__ W0, const float* __restrict__ Wa,
                           const float* __restrict__ W1) {
    int gid = blockIdx.x;
    int tid = threadIdx.x;
    if (gid < 4320) {
        int side = (gid >= 2160);
        int t = (gid - side * 2160) * 256 + tid;
        const float* X = side ? xf : xs;
        int r = t / 12, o = t - r * 12;
        unsigned short h8[8], l8[8];
#pragma unroll
        for (int j = 0; j < 8; j++) {
            int k = 8 * o + j;
            float x = (k < NODE) ? X[(size_t)r * NODE + k] : 0.f;
            unsigned short h = f2b(x);
            h8[j] = h;
            l8[j] = f2b(x - b2f(h));
        }
        unsigned short* ph = side ? g_xfhi : g_xshi;
        unsigned short* pl = side ? g_xflo : g_xslo;
        *(uint4*)&ph[(size_t)r * XLD + 8 * o] = *(uint4*)h8;
        *(uint4*)&pl[(size_t)r * XLD + 8 * o] = *(uint4*)l8;
    } else {
        const float* W;
        int K, Kpad, which, t;
        if (gid < 4332)      { W = W0; K = NODE; Kpad = XLD; which = 0; t = (gid - 4320) * 256 + tid; }
        else if (gid < 4364) { W = Wa; K = 256;  Kpad = 256; which = 1; t = (gid - 4332) * 256 + tid; }
        else                 { W = W1; K = 512;  Kpad = 512; which = 2; t = (gid - 4364) * 256 + tid; }
        int c = t / (Kpad / 8), o = t - c * (Kpad / 8);
        unsigned short h8[8], l8[8];
#pragma unroll
        for (int j = 0; j < 8; j++) {
            int k = 8 * o + j;
            float x = (k < K) ? W[(size_t)k * 256 + c] : 0.f;
            unsigned short h = f2b(x);
            h8[j] = h;
            l8[j] = f2b(x - b2f(h));
        }
        *(uint4*)&wthi(which)[(size_t)c * Kpad + 8 * o] = *(uint4*)h8;
        *(uint4*)&wtlo(which)[(size_t)c * Kpad + 8 * o] = *(uint4*)l8;
    }
}

// ---------------------------------------------------------------------------
// Two-sided MFMA bf16x2-split GEMM, FULL-WIDTH blocks (64 rows x 256 cols).
// A panel is fetched from HBM exactly ONCE (no column-block re-fetch); the
// whole W fits in L2. Blocks [0,nSide) = side S; [nSide,2nSide) = side F.
// emitT2=1: write hi/lo planes to g_t2* instead of fp32 g_T.
// ---------------------------------------------------------------------------
#define GK 32
#define ASTR 40
__global__ __launch_bounds__(256) void k_gemm_mfma(int xsA, int x2sA, int xsB, int x2sB,
                                                   int kld, int K, int wsel, int wld,
                                                   int emitT2, int nSide) {
    __shared__ unsigned short Ah[64][ASTR], Al[64][ASTR];
    __shared__ unsigned short Bh[256][ASTR], Bl[256][ASTR];
    int tid = threadIdx.x;
    int id = blockIdx.x;
    int side = (id >= nSide);
    int bm = side ? id - nSide : id;
    int r0 = bm * 64;
    int tbase = side ? NN : 0;
    int xsel = side ? xsB : xsA;
    int x2sel = side ? x2sB : x2sA;
    const unsigned short* whi_ = wthi(wsel);
    const unsigned short* wlo_ = wtlo(wsel);

    int w = tid >> 6;
    int l = tid & 63;
    int lr = l & 15;
    int lq = l >> 4;
    int koff = lq * 8;
    int sr = tid >> 2, so = (tid & 3) * 8;   // staging: row/col = sr, k-oct = so

    f32x4 acc[16];
#pragma unroll
    for (int c = 0; c < 16; c++) acc[c] = (f32x4){0.f, 0.f, 0.f, 0.f};

    int nt = K / GK;
    for (int t = 0; t < nt; t++) {
        int k0 = t * GK;
        const unsigned short *phi, *plo;
        int xc;
        if (x2sel >= 0 && k0 >= HID) { phi = selhi(x2sel); plo = sello(x2sel); xc = k0 - HID; }
        else                          { phi = selhi(xsel);  plo = sello(xsel);  xc = k0; }

        __syncthreads();
        {
            // A: 64 rows x 32k, one uint4/plane per thread
            size_t ga = (size_t)(r0 + sr) * kld + xc + so;
            *(uint4*)&Ah[sr][so] = *(const uint4*)&phi[ga];
            *(uint4*)&Al[sr][so] = *(const uint4*)&plo[ga];
            // B: 256 cols x 32k, four uint4/plane per thread
#pragma unroll
            for (int q = 0; q < 4; q++) {
                int i = tid + (q << 8);
                int col = i >> 2, oq = (i & 3) << 3;
                size_t gb = (size_t)col * wld + k0 + oq;
                *(uint4*)&Bh[col][oq] = *(const uint4*)&whi_[gb];
                *(uint4*)&Bl[col][oq] = *(const uint4*)&wlo_[gb];
            }
        }
        __syncthreads();

        bf16x8 ah = *(const bf16x8*)&Ah[16 * w + lr][koff];
        bf16x8 al = *(const bf16x8*)&Al[16 * w + lr][koff];
#pragma unroll
        for (int c = 0; c < 16; c++) {
            bf16x8 bh = *(const bf16x8*)&Bh[16 * c + lr][koff];
            bf16x8 bl = *(const bf16x8*)&Bl[16 * c + lr][koff];
            acc[c] = __builtin_amdgcn_mfma_f32_16x16x32_bf16(ah, bh, acc[c], 0, 0, 0);
            acc[c] = __builtin_amdgcn_mfma_f32_16x16x32_bf16(ah, bl, acc[c], 0, 0, 0);
            acc[c] = __builtin_amdgcn_mfma_f32_16x16x32_bf16(al, bh, acc[c], 0, 0, 0);
        }
    }

#pragma unroll
    for (int c = 0; c < 16; c++) {
#pragma unroll
        for (int qq = 0; qq < 4; qq++) {
            size_t row = (size_t)(tbase + r0 + 16 * w + 4 * lq + qq);
            size_t col = 16 * c + lr;
            float v = acc[c][qq];
            if (emitT2) {
                unsigned short h = f2b(v);
                g_t2hi[row * HID + col] = h;
                g_t2lo[row * HID + col] = f2b(v - b2f(h));
            } else {
                g_T[row * HID + col] = v;
            }
        }
    }
}

// ---------------------------------------------------------------------------
// Fused two-stream aggregate; emits h planes + d_out copy.
// ---------------------------------------------------------------------------
__global__ __launch_bounds__(256) void k_agg2(const float* __restrict__ bias,
                                              float* __restrict__ outS,
                                              float* __restrict__ outF) {
    __shared__ float AdjT[NODE][102];
    int tid = threadIdx.x;
    int idx = blockIdx.x;
    int side = idx >> 10;
    int b = (idx & 1023) >> 1;
    int c0 = (idx & 1) * 128;
    const float* Adj = adjPtr(side) + (size_t)b * NODE * NODE;
    const float* Tg = g_T + ((size_t)side * NN + (size_t)b * NODE) * HID;
    float* outp = side ? outF : outS;
    unsigned short* phD = selhi(side);
    unsigned short* plD = sello(side);

    for (int i = tid; i < NODE * NODE; i += 256) {
        int n = i / NODE, k = i - n * NODE;
        AdjT[k][n] = Adj[i];
    }
    for (int i = tid; i < NODE * 12; i += 256) {
        int k = i / 12, n = NODE + (i % 12);
        AdjT[k][n] = 0.f;
    }
    __syncthreads();

    int ti = tid & 15, tj = tid >> 4;
    int rbase = 6 * ti;
    int cc = c0 + 8 * tj;

    float acc[6][8];
#pragma unroll
    for (int i = 0; i < 6; i++)
#pragma unroll
        for (int j = 0; j < 8; j++) acc[i][j] = 0.f;

#pragma unroll 2
    for (int k = 0; k < NODE; k++) {
        float4 t0 = *(const float4*)&Tg[(size_t)k * HID + cc];
        float4 t1 = *(const float4*)&Tg[(size_t)k * HID + cc + 4];
        float bv[8] = {t0.x, t0.y, t0.z, t0.w, t1.x, t1.y, t1.z, t1.w};
        float2 a01 = *(const float2*)&AdjT[k][rbase];
        float2 a23 = *(const float2*)&AdjT[k][rbase + 2];
        float2 a45 = *(const float2*)&AdjT[k][rbase + 4];
        float av[6] = {a01.x, a01.y, a23.x, a23.y, a45.x, a45.y};
#pragma unroll
        for (int i = 0; i < 6; i++)
#pragma unroll
            for (int j = 0; j < 8; j++)
                acc[i][j] = fmaf(av[i], bv[j], acc[i][j]);
    }

    float bb[8];
#pragma unroll
    for (int j = 0; j < 8; j++) bb[j] = bias[cc + j];

#pragma unroll
    for (int i = 0; i < 6; i++) {
        int n = rbase + i;
        if (n < NODE) {
            size_t row = (size_t)(b * NODE + n);
            float v[8];
            unsigned short h8[8], l8[8];
#pragma unroll
            for (int j = 0; j < 8; j++) {
                v[j] = fmaxf(acc[i][j] + bb[j], 0.f);
                unsigned short h = f2b(v[j]);
                h8[j] = h;
                l8[j] = f2b(v[j] - b2f(h));
            }
            *(float4*)&outp[row * 512 + cc] = make_float4(v[0], v[1], v[2], v[3]);
            *(float4*)&outp[row * 512 + cc + 4] = make_float4(v[4], v[5], v[6], v[7]);
            *(uint4*)&phD[row * HID + cc] = *(uint4*)h8;
            *(uint4*)&plD[row * HID + cc] = *(uint4*)l8;
        }
    }
}

// ---------------------------------------------------------------------------
// Scores via MFMA (col<92 guard). P = row-softmax -> g_P; fn/gm vectors.
// ---------------------------------------------------------------------------
__global__ __launch_bounds__(256) void k_score_mfma(int hfsel) {
    __shared__ unsigned short Ah[96][ASTR], Al[96][ASTR];
    __shared__ unsigned short Bh[96][ASTR], Bl[96][ASTR];
    __shared__ float Pm[96][92];
    __shared__ float rmax_[96], rinv_[96], fn_[96], gm_[96];

    int b = blockIdx.x;
    int tid = threadIdx.x;
    const unsigned short* t2h = g_t2hi + (size_t)b * NODE * HID;
    const unsigned short* t2l = g_t2lo + (size_t)b * NODE * HID;
    const unsigned short* hfh = selhi(hfsel) + (size_t)b * NODE * HID;
    const unsigned short* hfl_ = sello(hfsel) + (size_t)b * NODE * HID;

    int w = tid >> 6, l = tid & 63;
    int lr = l & 15, lq = l >> 4, koff = 8 * lq;
    int wr = w >> 1, wc = w & 1;

    f32x4 acc[3][3];
#pragma unroll
    for (int i = 0; i < 3; i++)
#pragma unroll
        for (int j = 0; j < 3; j++) acc[i][j] = (f32x4){0.f, 0.f, 0.f, 0.f};

    const uint4 z4 = make_uint4(0, 0, 0, 0);
    for (int t = 0; t < 8; t++) {
        int k0 = 32 * t;
        __syncthreads();
        for (int i = tid; i < 96 * 4; i += 256) {
            int r = i >> 2, o = (i & 3) << 3;
            uint4 vah = z4, val = z4, vbh = z4, vbl = z4;
            if (r < NODE) {
                size_t g = (size_t)r * HID + k0 + o;
                vah = *(const uint4*)&t2h[g];
                val = *(const uint4*)&t2l[g];
                vbh = *(const uint4*)&hfh[g];
                vbl = *(const uint4*)&hfl_[g];
            }
            *(uint4*)&Ah[r][o] = vah;
            *(uint4*)&Al[r][o] = val;
            *(uint4*)&Bh[r][o] = vbh;
            *(uint4*)&Bl[r][o] = vbl;
        }
        __syncthreads();

        bf16x8 ah[3], al[3], bh[3], bl[3];
#pragma unroll
        for (int i = 0; i < 3; i++) {
            ah[i] = *(const bf16x8*)&Ah[48 * wr + 16 * i + lr][koff];
            al[i] = *(const bf16x8*)&Al[48 * wr + 16 * i + lr][koff];
            bh[i] = *(const bf16x8*)&Bh[48 * wc + 16 * i + lr][koff];
            bl[i] = *(const bf16x8*)&Bl[48 * wc + 16 * i + lr][koff];
        }
#pragma unroll
        for (int i = 0; i < 3; i++)
#pragma unroll
            for (int j = 0; j < 3; j++) {
                acc[i][j] = __builtin_amdgcn_mfma_f32_16x16x32_bf16(ah[i], bh[j], acc[i][j], 0, 0, 0);
                acc[i][j] = __builtin_amdgcn_mfma_f32_16x16x32_bf16(ah[i], bl[j], acc[i][j], 0, 0, 0);
                acc[i][j] = __builtin_amdgcn_mfma_f32_16x16x32_bf16(al[i], bh[j], acc[i][j], 0, 0, 0);
            }
    }

#pragma unroll
    for (int i = 0; i < 3; i++)
#pragma unroll
        for (int j = 0; j < 3; j++)
#pragma unroll
            for (int qq = 0; qq < 4; qq++) {
                int row = 48 * wr + 16 * i + 4 * lq + qq;
                int col = 48 * wc + 16 * j + lr;
                if (col < 92)
                    Pm[row][col] = tanh_safe(acc[i][j][qq]);
            }
    __syncthreads();

    if (tid < NODE) {
        int n = tid;
        float mx = -2.f;
        for (int m = 0; m < NODE; m++) mx = fmaxf(mx, Pm[n][m]);
        float s = 0.f;
        for (int m = 0; m < NODE; m++) s += __expf(Pm[n][m] - mx);
        rmax_[n] = mx;
        rinv_[n] = 1.f / s;
        fn_[n] = s * __expf(mx);
    } else if (tid >= 128 && tid < 128 + NODE) {
        int m = tid - 128;
        float mx = -2.f;
        for (int n = 0; n < NODE; n++) mx = fmaxf(mx, Pm[n][m]);
        float s = 0.f;
        for (int n = 0; n < NODE; n++) s += __expf(Pm[n][m] - mx);
        gm_[m] = __expf(-mx) / s;
    }
    __syncthreads();

    float* Pg = g_P + (size_t)b * NODE * NODE;
    for (int i = tid; i < NODE * NODE; i += 256) {
        int n = i / NODE, m = i - n * NODE;
        Pg[i] = __expf(Pm[n][m] - rmax_[n]) * rinv_[n];
    }
    if (tid < NODE) {
        g_fn[b * 96 + tid] = fn_[tid];
        g_gm[b * 96 + tid] = gm_[tid];
    }
}

// ---------------------------------------------------------------------------
// Merged PV: blocks [0,1024) = co_s, [1024,2048) = co_f. H from hi+lo planes.
// ---------------------------------------------------------------------------
__global__ __launch_bounds__(256) void k_pv(int fsel, int ssel, int cssel, int cfsel,
                                            float* __restrict__ outS,
                                            float* __restrict__ outF, int emit) {
    __shared__ float Pl[NODE][91];
    __shared__ float Hl[NODE][129];
    __shared__ float fnl[96], gml[96];
    int id = blockIdx.x;
    int isPV3 = (id >= 1024);
    int idL = isPV3 ? id - 1024 : id;
    int b = idL >> 1;
    int c0 = (idL & 1) * 128;
    int tid = threadIdx.x;

    const float* Pg = g_P + (size_t)b * NODE * NODE;
    for (int i = tid; i < NODE * NODE; i += 256) {
        int n = i / NODE, m = i - n * NODE;
        Pl[n][m] = Pg[i];
    }
    {
        int hsel = isPV3 ? ssel : fsel;
        const unsigned short* Hh = selhi(hsel) + (size_t)b * NODE * HID;
        const unsigned short* Hlo = sello(hsel) + (size_t)b * NODE * HID;
        for (int i = tid; i < NODE * 16; i += 256) {
            int r = i >> 4, o = (i & 15) << 3;
            uint4 vh = *(const uint4*)&Hh[(size_t)r * HID + c0 + o];
            uint4 vl = *(const uint4*)&Hlo[(size_t)r * HID + c0 + o];
            const unsigned short* ph = (const unsigned short*)&vh;
            const unsigned short* pl = (const unsigned short*)&vl;
#pragma unroll
            for (int j = 0; j < 8; j++)
                Hl[r][o + j] = b2f(ph[j]) + b2f(pl[j]);
        }
    }
    if (isPV3 && tid < 96) {
        fnl[tid] = (tid < NODE) ? g_fn[b * 96 + tid] : 0.f;
        gml[tid] = (tid < NODE) ? g_gm[b * 96 + tid] : 0.f;
    }
    __syncthreads();

    int c4 = (tid & 31) << 2;
    int rg = tid >> 5;
    float acc[12][4];
#pragma unroll
    for (int k = 0; k < 12; k++)
#pragma unroll
        for (int j = 0; j < 4; j++) acc[k][j] = 0.f;

    if (!isPV3) {
#pragma unroll 2
        for (int m = 0; m < NODE; m++) {
            float4 h = *(const float4*)&Hl[m][c4];
#pragma unroll
            for (int k = 0; k < 12; k++) {
                int n = rg + 8 * k;
                float p = Pl[(n < NODE) ? n : 0][m];
                acc[k][0] = fmaf(p, h.x, acc[k][0]);
                acc[k][1] = fmaf(p, h.y, acc[k][1]);
                acc[k][2] = fmaf(p, h.z, acc[k][2]);
                acc[k][3] = fmaf(p, h.w, acc[k][3]);
            }
        }
        unsigned short* csh = selhi(cssel);
        unsigned short* csl = sello(cssel);
#pragma unroll
        for (int k = 0; k < 12; k++) {
            int n = rg + 8 * k;
            if (n < NODE) {
                size_t row = (size_t)(b * NODE + n);
                size_t gc = c0 + c4;
                *(float4*)&outS[row * 512 + gc] =
                    make_float4(acc[k][0], acc[k][1], acc[k][2], acc[k][3]);
                if (emit) {
                    unsigned short h4[4], l4[4];
#pragma unroll
                    for (int j = 0; j < 4; j++) {
                        unsigned short h = f2b(acc[k][j]);
                        h4[j] = h;
                        l4[j] = f2b(acc[k][j] - b2f(h));
                    }
                    *(uint2*)&csh[row * HID + gc] = *(uint2*)h4;
                    *(uint2*)&csl[row * HID + gc] = *(uint2*)l4;
                }
            }
        }
    } else {
#pragma unroll 2
        for (int n = 0; n < NODE; n++) {
            float4 h = *(const float4*)&Hl[n][c4];
            float f = fnl[n];
#pragma unroll
            for (int k = 0; k < 12; k++) {
                int m = rg + 8 * k;
                float p = Pl[n][(m < NODE) ? m : 0] * f;
                acc[k][0] = fmaf(p, h.x, acc[k][0]);
                acc[k][1] = fmaf(p, h.y, acc[k][1]);
                acc[k][2] = fmaf(p, h.z, acc[k][2]);
                acc[k][3] = fmaf(p, h.w, acc[k][3]);
            }
        }
        unsigned short* cfh = selhi(cfsel);
        unsigned short* cfl = sello(cfsel);
#pragma unroll
        for (int k = 0; k < 12; k++) {
            int m = rg + 8 * k;
            if (m < NODE) {
                float g = gml[m];
                size_t row = (size_t)(b * NODE + m);
                size_t gc = c0 + c4;
                float o4[4] = {acc[k][0] * g, acc[k][1] * g, acc[k][2] * g, acc[k][3] * g};
                *(float4*)&outF[row * 512 + gc] = make_float4(o4[0], o4[1], o4[2], o4[3]);
                if (emit) {
                    unsigned short h4[4], l4[4];
#pragma unroll
                    for (int j = 0; j < 4; j++) {
                        unsigned short h = f2b(o4[j]);
                        h4[j] = h;
                        l4[j] = f2b(o4[j] - b2f(h));
                    }
                    *(uint2*)&cfh[row * HID + gc] = *(uint2*)h4;
                    *(uint2*)&cfl[row * HID + gc] = *(uint2*)l4;
                }
            }
        }
    }
}

// ---------------------------------------------------------------------------
extern "C" void kernel_launch(void* const* d_in, const int* in_sizes, int n_in,
                              void* d_out, int out_size, void* d_ws, size_t ws_size,
                              hipStream_t stream) {
    const float* x_sc = (const float*)d_in[0];
    const void* e_sc = d_in[1];
    const float* x_fc = (const float*)d_in[2];
    const void* e_fc = d_in[3];
    const float* W0 = (const float*)d_in[4];
    const float* b0 = (const float*)d_in[5];
    const float* W1 = (const float*)d_in[6];
    const float* b1 = (const float*)d_in[7];
    const float* Wa = (const float*)d_in[8];

    float* out = (float*)d_out;
    size_t os = (size_t)NN * 512;
    float* x1s = out;
    float* x2s = out + os;
    float* x1f = out + 2 * os;
    float* x2f = out + 3 * os;

    const int NS = NN / 64;          // 720 row-blocks per side

    k_adj_fused<<<1024, 256, 0, stream>>>(e_sc, e_fc);
    k_conv_all<<<4428, 256, 0, stream>>>(x_sc, x_fc, W0, Wa, W1);

    // ---- layer 1 (both sides, full-width blocks) ----
    k_gemm_mfma<<<2 * NS, 256, 0, stream>>>(4, -1, 5, -1, XLD, XLD, 0, XLD, 0, NS);
    k_agg2<<<2048, 256, 0, stream>>>(b0, x1s, x1f);

    // ---- co-attention 1 ----
    k_gemm_mfma<<<NS, 256, 0, stream>>>(0, -1, 0, -1, HID, 256, 1, 256, 1, NS);
    k_score_mfma<<<NB, 256, 0, stream>>>(1);
    k_pv<<<2048, 256, 0, stream>>>(1, 0, 2, 3, x1s + HID, x1f + HID, 1);

    // ---- layer 2 (both sides) ----
    k_gemm_mfma<<<2 * NS, 256, 0, stream>>>(0, 2, 1, 3, HID, 512, 2, 512, 0, NS);
    k_agg2<<<2048, 256, 0, stream>>>(b1, x2s, x2f);

    // ---- co-attention 2 ----
    k_gemm_mfma<<<NS, 256, 0, stream>>>(0, -1, 0, -1, HID, 256, 1, 256, 1, NS);
    k_score_mfma<<<NB, 256, 0, stream>>>(1);
    k_pv<<<2048, 256, 0, stream>>>(1, 0, 2, 3, x2s + HID, x2f + HID, 0);
}

// Round 19
// 837.776 us; speedup vs baseline: 1.3613x; 1.0008x over previous
//
#include <hip/hip_runtime.h>
#include <hip/hip_bf16.h>
#include <math.h>

#define NODE 90
#define HID 256
#define NB 512
#define NN (NB * 90)
#define EDGES (NB * 2700)
#define XLD 96

typedef __attribute__((ext_vector_type(8))) short bf16x8;
typedef __attribute__((ext_vector_type(4))) float f32x4;

__device__ __forceinline__ float tanh_safe(float s) {
    s = fminf(fmaxf(s, -15.f), 15.f);
    float t = __expf(2.f * s);
    return (t - 1.f) / (t + 1.f);
}
__device__ __forceinline__ unsigned short f2b(float x) {
    unsigned u = __float_as_uint(x);
    return (unsigned short)((u + 0x7FFFu + ((u >> 16) & 1u)) >> 16);
}
__device__ __forceinline__ float b2f(unsigned short h) {
    return __uint_as_float(((unsigned)h) << 16);
}

// ---------------------------------------------------------------------------
__device__ float g_adjS[(size_t)NB * NODE * NODE];
__device__ float g_adjF[(size_t)NB * NODE * NODE];
__device__ float g_T[(size_t)2 * NN * HID];
__device__ float g_P[(size_t)NB * NODE * NODE];
__device__ float g_fn[NB * 96];
__device__ float g_gm[NB * 96];

__device__ unsigned short g_hshi[(size_t)NN * HID], g_hslo[(size_t)NN * HID];
__device__ unsigned short g_hfhi[(size_t)NN * HID], g_hflo[(size_t)NN * HID];
__device__ unsigned short g_cshi[(size_t)NN * HID], g_cslo[(size_t)NN * HID];
__device__ unsigned short g_cfhi[(size_t)NN * HID], g_cflo[(size_t)NN * HID];
__device__ unsigned short g_xshi[(size_t)NN * XLD], g_xslo[(size_t)NN * XLD];
__device__ unsigned short g_xfhi[(size_t)NN * XLD], g_xflo[(size_t)NN * XLD];
__device__ unsigned short g_t2hi[(size_t)NN * HID], g_t2lo[(size_t)NN * HID];
__device__ unsigned short g_w0thi[256 * XLD], g_w0tlo[256 * XLD];
__device__ unsigned short g_wathi[256 * 256], g_watlo[256 * 256];
__device__ unsigned short g_w1thi[256 * 512], g_w1tlo[256 * 512];

__device__ __forceinline__ float* adjPtr(int w) { return w ? g_adjF : g_adjS; }
__device__ __forceinline__ unsigned short* selhi(int w) {
    switch (w) {
        case 0: return g_hshi;
        case 1: return g_hfhi;
        case 2: return g_cshi;
        case 3: return g_cfhi;
        case 4: return g_xshi;
        default: return g_xfhi;
    }
}
__device__ __forceinline__ unsigned short* sello(int w) {
    switch (w) {
        case 0: return g_hslo;
        case 1: return g_hflo;
        case 2: return g_cslo;
        case 3: return g_cflo;
        case 4: return g_xslo;
        default: return g_xflo;
    }
}
__device__ __forceinline__ unsigned short* wthi(int w) {
    switch (w) { case 0: return g_w0thi; case 1: return g_wathi; default: return g_w1thi; }
}
__device__ __forceinline__ unsigned short* wtlo(int w) {
    switch (w) { case 0: return g_w0tlo; case 1: return g_watlo; default: return g_w1tlo; }
}

// ---------------------------------------------------------------------------
// Fused adjacency with block-local dtype detection (deterministic).
// ---------------------------------------------------------------------------
__global__ __launch_bounds__(256) void k_adj_fused(const void* __restrict__ eS,
                                                   const void* __restrict__ eF) {
    __shared__ float cnt[NODE][NODE + 1];
    __shared__ float dinv[NODE];
    __shared__ int s_e64;
    int side = blockIdx.x >> 9;
    int b = blockIdx.x & 511;
    const void* edges = side ? eF : eS;
    int tid = threadIdx.x;
    const int* p32 = (const int*)edges;
    if (tid == 0) s_e64 = 1;
    for (int i = tid; i < NODE * (NODE + 1); i += 256) (&cnt[0][0])[i] = 0.f;
    __syncthreads();
    for (int i = tid; i < 1024; i += 256)
        if (p32[2 * i + 1] != 0) s_e64 = 0;
    __syncthreads();
    int e64 = s_e64;
    const long long* p64 = (const long long*)edges;
    for (int i = tid; i < 2700; i += 256) {
        int idx = b * 2700 + i;
        long long s, d;
        if (e64) { s = p64[idx]; d = p64[EDGES + idx]; }
        else     { s = p32[idx]; d = p32[EDGES + idx]; }
        int sl = (int)s - b * NODE, dl = (int)d - b * NODE;
        if (sl >= 0 && sl < NODE && dl >= 0 && dl < NODE)
            atomicAdd(&cnt[dl][sl], 1.0f);
    }
    __syncthreads();
    if (tid < NODE) {
        float s = 0.f;
        for (int k = 0; k < NODE; k++) s += cnt[tid][k];
        dinv[tid] = (s > 0.f) ? rsqrtf(s) : 0.f;
    }
    __syncthreads();
    float* adj = adjPtr(side) + (size_t)b * NODE * NODE;
    for (int i = tid; i < NODE * NODE; i += 256) {
        int d = i / NODE, s = i - d * NODE;
        adj[i] = cnt[d][s] * dinv[d] * dinv[s];
    }
}

// ---------------------------------------------------------------------------
// All input conversions in ONE dispatch.
// ---------------------------------------------------------------------------
__global__ void k_conv_all(const float* __restrict__ xs, const float* __restrict__ xf,
                           const float* __restrict__ W0, const float* __restrict__ Wa,
                           const float* __restrict__ W1) {
    int gid = blockIdx.x;
    int tid = threadIdx.x;
    if (gid < 4320) {
        int side = (gid >= 2160);
        int t = (gid - side * 2160) * 256 + tid;
        const float* X = side ? xf : xs;
        int r = t / 12, o = t - r * 12;
        unsigned short h8[8], l8[8];
#pragma unroll
        for (int j = 0; j < 8; j++) {
            int k = 8 * o + j;
            float x = (k < NODE) ? X[(size_t)r * NODE + k] : 0.f;
            unsigned short h = f2b(x);
            h8[j] = h;
            l8[j] = f2b(x - b2f(h));
        }
        unsigned short* ph = side ? g_xfhi : g_xshi;
        unsigned short* pl = side ? g_xflo : g_xslo;
        *(uint4*)&ph[(size_t)r * XLD + 8 * o] = *(uint4*)h8;
        *(uint4*)&pl[(size_t)r * XLD + 8 * o] = *(uint4*)l8;
    } else {
        const float* W;
        int K, Kpad, which, t;
        if (gid < 4332)      { W = W0; K = NODE; Kpad = XLD; which = 0; t = (gid - 4320) * 256 + tid; }
        else if (gid < 4364) { W = Wa; K = 256;  Kpad = 256; which = 1; t = (gid - 4332) * 256 + tid; }
        else                 { W = W1; K = 512;  Kpad = 512; which = 2; t = (gid - 4364) * 256 + tid; }
        int c = t / (Kpad / 8), o = t - c * (Kpad / 8);
        unsigned short h8[8], l8[8];
#pragma unroll
        for (int j = 0; j < 8; j++) {
            int k = 8 * o + j;
            float x = (k < K) ? W[(size_t)k * 256 + c] : 0.f;
            unsigned short h = f2b(x);
            h8[j] = h;
            l8[j] = f2b(x - b2f(h));
        }
        *(uint4*)&wthi(which)[(size_t)c * Kpad + 8 * o] = *(uint4*)h8;
        *(uint4*)&wtlo(which)[(size_t)c * Kpad + 8 * o] = *(uint4*)l8;
    }
}

// ---------------------------------------------------------------------------
// Two-sided MFMA bf16x2-split GEMM, FULL-WIDTH blocks (64 rows x 256 cols).
// A panel is fetched from HBM exactly ONCE (no column-block re-fetch); the
// whole W fits in L2. Blocks [0,nSide) = side S; [nSide,2nSide) = side F.
// emitT2=1: write hi/lo planes to g_t2* instead of fp32 g_T.
// ---------------------------------------------------------------------------
#define GK 32
#define ASTR 40
__global__ __launch_bounds__(256) void k_gemm_mfma(int xsA, int x2sA, int xsB, int x2sB,
                                                   int kld, int K, int wsel, int wld,
                                                   int emitT2, int nSide) {
    __shared__ unsigned short Ah[64][ASTR], Al[64][ASTR];
    __shared__ unsigned short Bh[256][ASTR], Bl[256][ASTR];
    int tid = threadIdx.x;
    int id = blockIdx.x;
    int side = (id >= nSide);
    int bm = side ? id - nSide : id;
    int r0 = bm * 64;
    int tbase = side ? NN : 0;
    int xsel = side ? xsB : xsA;
    int x2sel = side ? x2sB : x2sA;
    const unsigned short* whi_ = wthi(wsel);
    const unsigned short* wlo_ = wtlo(wsel);

    int w = tid >> 6;
    int l = tid & 63;
    int lr = l & 15;
    int lq = l >> 4;
    int koff = lq * 8;
    int sr = tid >> 2, so = (tid & 3) * 8;   // staging: row/col = sr, k-oct = so

    f32x4 acc[16];
#pragma unroll
    for (int c = 0; c < 16; c++) acc[c] = (f32x4){0.f, 0.f, 0.f, 0.f};

    int nt = K / GK;
    for (int t = 0; t < nt; t++) {
        int k0 = t * GK;
        const unsigned short *phi, *plo;
        int xc;
        if (x2sel >= 0 && k0 >= HID) { phi = selhi(x2sel); plo = sello(x2sel); xc = k0 - HID; }
        else                          { phi = selhi(xsel);  plo = sello(xsel);  xc = k0; }

        __syncthreads();
        {
            // A: 64 rows x 32k, one uint4/plane per thread
            size_t ga = (size_t)(r0 + sr) * kld + xc + so;
            *(uint4*)&Ah[sr][so] = *(const uint4*)&phi[ga];
            *(uint4*)&Al[sr][so] = *(const uint4*)&plo[ga];
            // B: 256 cols x 32k, four uint4/plane per thread
#pragma unroll
            for (int q = 0; q < 4; q++) {
                int i = tid + (q << 8);
                int col = i >> 2, oq = (i & 3) << 3;
                size_t gb = (size_t)col * wld + k0 + oq;
                *(uint4*)&Bh[col][oq] = *(const uint4*)&whi_[gb];
                *(uint4*)&Bl[col][oq] = *(const uint4*)&wlo_[gb];
            }
        }
        __syncthreads();

        bf16x8 ah = *(const bf16x8*)&Ah[16 * w + lr][koff];
        bf16x8 al = *(const bf16x8*)&Al[16 * w + lr][koff];
#pragma unroll
        for (int c = 0; c < 16; c++) {
            bf16x8 bh = *(const bf16x8*)&Bh[16 * c + lr][koff];
            bf16x8 bl = *(const bf16x8*)&Bl[16 * c + lr][koff];
            acc[c] = __builtin_amdgcn_mfma_f32_16x16x32_bf16(ah, bh, acc[c], 0, 0, 0);
            acc[c] = __builtin_amdgcn_mfma_f32_16x16x32_bf16(ah, bl, acc[c], 0, 0, 0);
            acc[c] = __builtin_amdgcn_mfma_f32_16x16x32_bf16(al, bh, acc[c], 0, 0, 0);
        }
    }

#pragma unroll
    for (int c = 0; c < 16; c++) {
#pragma unroll
        for (int qq = 0; qq < 4; qq++) {
            size_t row = (size_t)(tbase + r0 + 16 * w + 4 * lq + qq);
            size_t col = 16 * c + lr;
            float v = acc[c][qq];
            if (emitT2) {
                unsigned short h = f2b(v);
                g_t2hi[row * HID + col] = h;
                g_t2lo[row * HID + col] = f2b(v - b2f(h));
            } else {
                g_T[row * HID + col] = v;
            }
        }
    }
}

// ---------------------------------------------------------------------------
// Fused two-stream aggregate; emits h planes + d_out copy.
// ---------------------------------------------------------------------------
__global__ __launch_bounds__(256) void k_agg2(const float* __restrict__ bias,
                                              float* __restrict__ outS,
                                              float* __restrict__ outF) {
    __shared__ float AdjT[NODE][102];
    int tid = threadIdx.x;
    int idx = blockIdx.x;
    int side = idx >> 10;
    int b = (idx & 1023) >> 1;
    int c0 = (idx & 1) * 128;
    const float* Adj = adjPtr(side) + (size_t)b * NODE * NODE;
    const float* Tg = g_T + ((size_t)side * NN + (size_t)b * NODE) * HID;
    float* outp = side ? outF : outS;
    unsigned short* phD = selhi(side);
    unsigned short* plD = sello(side);

    for (int i = tid; i < NODE * NODE; i += 256) {
        int n = i / NODE, k = i - n * NODE;
        AdjT[k][n] = Adj[i];
    }
    for (int i = tid; i < NODE * 12; i += 256) {
        int k = i / 12, n = NODE + (i % 12);
        AdjT[k][n] = 0.f;
    }
    __syncthreads();

    int ti = tid & 15, tj = tid >> 4;
    int rbase = 6 * ti;
    int cc = c0 + 8 * tj;

    float acc[6][8];
#pragma unroll
    for (int i = 0; i < 6; i++)
#pragma unroll
        for (int j = 0; j < 8; j++) acc[i][j] = 0.f;

#pragma unroll 2
    for (int k = 0; k < NODE; k++) {
        float4 t0 = *(const float4*)&Tg[(size_t)k * HID + cc];
        float4 t1 = *(const float4*)&Tg[(size_t)k * HID + cc + 4];
        float bv[8] = {t0.x, t0.y, t0.z, t0.w, t1.x, t1.y, t1.z, t1.w};
        float2 a01 = *(const float2*)&AdjT[k][rbase];
        float2 a23 = *(const float2*)&AdjT[k][rbase + 2];
        float2 a45 = *(const float2*)&AdjT[k][rbase + 4];
        float av[6] = {a01.x, a01.y, a23.x, a23.y, a45.x, a45.y};
#pragma unroll
        for (int i = 0; i < 6; i++)
#pragma unroll
            for (int j = 0; j < 8; j++)
                acc[i][j] = fmaf(av[i], bv[j], acc[i][j]);
    }

    float bb[8];
#pragma unroll
    for (int j = 0; j < 8; j++) bb[j] = bias[cc + j];

#pragma unroll
    for (int i = 0; i < 6; i++) {
        int n = rbase + i;
        if (n < NODE) {
            size_t row = (size_t)(b * NODE + n);
            float v[8];
            unsigned short h8[8], l8[8];
#pragma unroll
            for (int j = 0; j < 8; j++) {
                v[j] = fmaxf(acc[i][j] + bb[j], 0.f);
                unsigned short h = f2b(v[j]);
                h8[j] = h;
                l8[j] = f2b(v[j] - b2f(h));
            }
            *(float4*)&outp[row * 512 + cc] = make_float4(v[0], v[1], v[2], v[3]);
            *(float4*)&outp[row * 512 + cc + 4] = make_float4(v[4], v[5], v[6], v[7]);
            *(uint4*)&phD[row * HID + cc] = *(uint4*)h8;
            *(uint4*)&plD[row * HID + cc] = *(uint4*)l8;
        }
    }
}

// ---------------------------------------------------------------------------
// Scores via MFMA (col<92 guard). P = row-softmax -> g_P; fn/gm vectors.
// ---------------------------------------------------------------------------
__global__ __launch_bounds__(256) void k_score_mfma(int hfsel) {
    __shared__ unsigned short Ah[96][ASTR], Al[96][ASTR];
    __shared__ unsigned short Bh[96][ASTR], Bl[96][ASTR];
    __shared__ float Pm[96][92];
    __shared__ float rmax_[96], rinv_[96], fn_[96], gm_[96];

    int b = blockIdx.x;
    int tid = threadIdx.x;
    const unsigned short* t2h = g_t2hi + (size_t)b * NODE * HID;
    const unsigned short* t2l = g_t2lo + (size_t)b * NODE * HID;
    const unsigned short* hfh = selhi(hfsel) + (size_t)b * NODE * HID;
    const unsigned short* hfl_ = sello(hfsel) + (size_t)b * NODE * HID;

    int w = tid >> 6, l = tid & 63;
    int lr = l & 15, lq = l >> 4, koff = 8 * lq;
    int wr = w >> 1, wc = w & 1;

    f32x4 acc[3][3];
#pragma unroll
    for (int i = 0; i < 3; i++)
#pragma unroll
        for (int j = 0; j < 3; j++) acc[i][j] = (f32x4){0.f, 0.f, 0.f, 0.f};

    const uint4 z4 = make_uint4(0, 0, 0, 0);
    for (int t = 0; t < 8; t++) {
        int k0 = 32 * t;
        __syncthreads();
        for (int i = tid; i < 96 * 4; i += 256) {
            int r = i >> 2, o = (i & 3) << 3;
            uint4 vah = z4, val = z4, vbh = z4, vbl = z4;
            if (r < NODE) {
                size_t g = (size_t)r * HID + k0 + o;
                vah = *(const uint4*)&t2h[g];
                val = *(const uint4*)&t2l[g];
                vbh = *(const uint4*)&hfh[g];
                vbl = *(const uint4*)&hfl_[g];
            }
            *(uint4*)&Ah[r][o] = vah;
            *(uint4*)&Al[r][o] = val;
            *(uint4*)&Bh[r][o] = vbh;
            *(uint4*)&Bl[r][o] = vbl;
        }
        __syncthreads();

        bf16x8 ah[3], al[3], bh[3], bl[3];
#pragma unroll
        for (int i = 0; i < 3; i++) {
            ah[i] = *(const bf16x8*)&Ah[48 * wr + 16 * i + lr][koff];
            al[i] = *(const bf16x8*)&Al[48 * wr + 16 * i + lr][koff];
            bh[i] = *(const bf16x8*)&Bh[48 * wc + 16 * i + lr][koff];
            bl[i] = *(const bf16x8*)&Bl[48 * wc + 16 * i + lr][koff];
        }
#pragma unroll
        for (int i = 0; i < 3; i++)
#pragma unroll
            for (int j = 0; j < 3; j++) {
                acc[i][j] = __builtin_amdgcn_mfma_f32_16x16x32_bf16(ah[i], bh[j], acc[i][j], 0, 0, 0);
                acc[i][j] = __builtin_amdgcn_mfma_f32_16x16x32_bf16(ah[i], bl[j], acc[i][j], 0, 0, 0);
                acc[i][j] = __builtin_amdgcn_mfma_f32_16x16x32_bf16(al[i], bh[j], acc[i][j], 0, 0, 0);
            }
    }

#pragma unroll
    for (int i = 0; i < 3; i++)
#pragma unroll
        for (int j = 0; j < 3; j++)
#pragma unroll
            for (int qq = 0; qq < 4; qq++) {
                int row = 48 * wr + 16 * i + 4 * lq + qq;
                int col = 48 * wc + 16 * j + lr;
                if (col < 92)
                    Pm[row][col] = tanh_safe(acc[i][j][qq]);
            }
    __syncthreads();

    if (tid < NODE) {
        int n = tid;
        float mx = -2.f;
        for (int m = 0; m < NODE; m++) mx = fmaxf(mx, Pm[n][m]);
        float s = 0.f;
        for (int m = 0; m < NODE; m++) s += __expf(Pm[n][m] - mx);
        rmax_[n] = mx;
        rinv_[n] = 1.f / s;
        fn_[n] = s * __expf(mx);
    } else if (tid >= 128 && tid < 128 + NODE) {
        int m = tid - 128;
        float mx = -2.f;
        for (int n = 0; n < NODE; n++) mx = fmaxf(mx, Pm[n][m]);
        float s = 0.f;
        for (int n = 0; n < NODE; n++) s += __expf(Pm[n][m] - mx);
        gm_[m] = __expf(-mx) / s;
    }
    __syncthreads();

    float* Pg = g_P + (size_t)b * NODE * NODE;
    for (int i = tid; i < NODE * NODE; i += 256) {
        int n = i / NODE, m = i - n * NODE;
        Pg[i] = __expf(Pm[n][m] - rmax_[n]) * rinv_[n];
    }
    if (tid < NODE) {
        g_fn[b * 96 + tid] = fn_[tid];
        g_gm[b * 96 + tid] = gm_[tid];
    }
}

// ---------------------------------------------------------------------------
// Merged PV: blocks [0,1024) = co_s, [1024,2048) = co_f. H from hi+lo planes.
// ---------------------------------------------------------------------------
__global__ __launch_bounds__(256) void k_pv(int fsel, int ssel, int cssel, int cfsel,
                                            float* __restrict__ outS,
                                            float* __restrict__ outF, int emit) {
    __shared__ float Pl[NODE][91];
    __shared__ float Hl[NODE][129];
    __shared__ float fnl[96], gml[96];
    int id = blockIdx.x;
    int isPV3 = (id >= 1024);
    int idL = isPV3 ? id - 1024 : id;
    int b = idL >> 1;
    int c0 = (idL & 1) * 128;
    int tid = threadIdx.x;

    const float* Pg = g_P + (size_t)b * NODE * NODE;
    for (int i = tid; i < NODE * NODE; i += 256) {
        int n = i / NODE, m = i - n * NODE;
        Pl[n][m] = Pg[i];
    }
    {
        int hsel = isPV3 ? ssel : fsel;
        const unsigned short* Hh = selhi(hsel) + (size_t)b * NODE * HID;
        const unsigned short* Hlo = sello(hsel) + (size_t)b * NODE * HID;
        for (int i = tid; i < NODE * 16; i += 256) {
            int r = i >> 4, o = (i & 15) << 3;
            uint4 vh = *(const uint4*)&Hh[(size_t)r * HID + c0 + o];
            uint4 vl = *(const uint4*)&Hlo[(size_t)r * HID + c0 + o];
            const unsigned short* ph = (const unsigned short*)&vh;
            const unsigned short* pl = (const unsigned short*)&vl;
#pragma unroll
            for (int j = 0; j < 8; j++)
                Hl[r][o + j] = b2f(ph[j]) + b2f(pl[j]);
        }
    }
    if (isPV3 && tid < 96) {
        fnl[tid] = (tid < NODE) ? g_fn[b * 96 + tid] : 0.f;
        gml[tid] = (tid < NODE) ? g_gm[b * 96 + tid] : 0.f;
    }
    __syncthreads();

    int c4 = (tid & 31) << 2;
    int rg = tid >> 5;
    float acc[12][4];
#pragma unroll
    for (int k = 0; k < 12; k++)
#pragma unroll
        for (int j = 0; j < 4; j++) acc[k][j] = 0.f;

    if (!isPV3) {
#pragma unroll 2
        for (int m = 0; m < NODE; m++) {
            float4 h = *(const float4*)&Hl[m][c4];
#pragma unroll
            for (int k = 0; k < 12; k++) {
                int n = rg + 8 * k;
                float p = Pl[(n < NODE) ? n : 0][m];
                acc[k][0] = fmaf(p, h.x, acc[k][0]);
                acc[k][1] = fmaf(p, h.y, acc[k][1]);
                acc[k][2] = fmaf(p, h.z, acc[k][2]);
                acc[k][3] = fmaf(p, h.w, acc[k][3]);
            }
        }
        unsigned short* csh = selhi(cssel);
        unsigned short* csl = sello(cssel);
#pragma unroll
        for (int k = 0; k < 12; k++) {
            int n = rg + 8 * k;
            if (n < NODE) {
                size_t row = (size_t)(b * NODE + n);
                size_t gc = c0 + c4;
                *(float4*)&outS[row * 512 + gc] =
                    make_float4(acc[k][0], acc[k][1], acc[k][2], acc[k][3]);
                if (emit) {
                    unsigned short h4[4], l4[4];
#pragma unroll
                    for (int j = 0; j < 4; j++) {
                        unsigned short h = f2b(acc[k][j]);
                        h4[j] = h;
                        l4[j] = f2b(acc[k][j] - b2f(h));
                    }
                    *(uint2*)&csh[row * HID + gc] = *(uint2*)h4;
                    *(uint2*)&csl[row * HID + gc] = *(uint2*)l4;
                }
            }
        }
    } else {
#pragma unroll 2
        for (int n = 0; n < NODE; n++) {
            float4 h = *(const float4*)&Hl[n][c4];
            float f = fnl[n];
#pragma unroll
            for (int k = 0; k < 12; k++) {
                int m = rg + 8 * k;
                float p = Pl[n][(m < NODE) ? m : 0] * f;
                acc[k][0] = fmaf(p, h.x, acc[k][0]);
                acc[k][1] = fmaf(p, h.y, acc[k][1]);
                acc[k][2] = fmaf(p, h.z, acc[k][2]);
                acc[k][3] = fmaf(p, h.w, acc[k][3]);
            }
        }
        unsigned short* cfh = selhi(cfsel);
        unsigned short* cfl = sello(cfsel);
#pragma unroll
        for (int k = 0; k < 12; k++) {
            int m = rg + 8 * k;
            if (m < NODE) {
                float g = gml[m];
                size_t row = (size_t)(b * NODE + m);
                size_t gc = c0 + c4;
                float o4[4] = {acc[k][0] * g, acc[k][1] * g, acc[k][2] * g, acc[k][3] * g};
                *(float4*)&outF[row * 512 + gc] = make_float4(o4[0], o4[1], o4[2], o4[3]);
                if (emit) {
                    unsigned short h4[4], l4[4];
#pragma unroll
                    for (int j = 0; j < 4; j++) {
                        unsigned short h = f2b(o4[j]);
                        h4[j] = h;
                        l4[j] = f2b(o4[j] - b2f(h));
                    }
                    *(uint2*)&cfh[row * HID + gc] = *(uint2*)h4;
                    *(uint2*)&cfl[row * HID + gc] = *(uint2*)l4;
                }
            }
        }
    }
}

// ---------------------------------------------------------------------------
extern "C" void kernel_launch(void* const* d_in, const int* in_sizes, int n_in,
                              void* d_out, int out_size, void* d_ws, size_t ws_size,
                              hipStream_t stream) {
    const float* x_sc = (const float*)d_in[0];
    const void* e_sc = d_in[1];
    const float* x_fc = (const float*)d_in[2];
    const void* e_fc = d_in[3];
    const float* W0 = (const float*)d_in[4];
    const float* b0 = (const float*)d_in[5];
    const float* W1 = (const float*)d_in[6];
    const float* b1 = (const float*)d_in[7];
    const float* Wa = (const float*)d_in[8];

    float* out = (float*)d_out;
    size_t os = (size_t)NN * 512;
    float* x1s = out;
    float* x2s = out + os;
    float* x1f = out + 2 * os;
    float* x2f = out + 3 * os;

    const int NS = NN / 64;          // 720 row-blocks per side

    k_adj_fused<<<1024, 256, 0, stream>>>(e_sc, e_fc);
    k_conv_all<<<4428, 256, 0, stream>>>(x_sc, x_fc, W0, Wa, W1);

    // ---- layer 1 (both sides, full-width blocks) ----
    k_gemm_mfma<<<2 * NS, 256, 0, stream>>>(4, -1, 5, -1, XLD, XLD, 0, XLD, 0, NS);
    k_agg2<<<2048, 256, 0, stream>>>(b0, x1s, x1f);

    // ---- co-attention 1 ----
    k_gemm_mfma<<<NS, 256, 0, stream>>>(0, -1, 0, -1, HID, 256, 1, 256, 1, NS);
    k_score_mfma<<<NB, 256, 0, stream>>>(1);
    k_pv<<<2048, 256, 0, stream>>>(1, 0, 2, 3, x1s + HID, x1f + HID, 1);

    // ---- layer 2 (both sides) ----
    k_gemm_mfma<<<2 * NS, 256, 0, stream>>>(0, 2, 1, 3, HID, 512, 2, 512, 0, NS);
    k_agg2<<<2048, 256, 0, stream>>>(b1, x2s, x2f);

    // ---- co-attention 2 ----
    k_gemm_mfma<<<NS, 256, 0, stream>>>(0, -1, 0, -1, HID, 256, 1, 256, 1, NS);
    k_score_mfma<<<NB, 256, 0, stream>>>(1);
    k_pv<<<2048, 256, 0, stream>>>(1, 0, 2, 3, x2s + HID, x2f + HID, 0);
}

// Round 20
// 767.056 us; speedup vs baseline: 1.4868x; 1.0922x over previous
//
#include <hip/hip_runtime.h>
#include <hip/hip_bf16.h>
#include <math.h>

#define NODE 90
#define HID 256
#define NB 512
#define NN (NB * 90)
#define EDGES (NB * 2700)
#define XLD 96

typedef __attribute__((ext_vector_type(8))) short bf16x8;
typedef __attribute__((ext_vector_type(4))) float f32x4;

__device__ __forceinline__ float tanh_safe(float s) {
    s = fminf(fmaxf(s, -15.f), 15.f);
    float t = __expf(2.f * s);
    return (t - 1.f) / (t + 1.f);
}
__device__ __forceinline__ unsigned short f2b(float x) {
    unsigned u = __float_as_uint(x);
    return (unsigned short)((u + 0x7FFFu + ((u >> 16) & 1u)) >> 16);
}
__device__ __forceinline__ float b2f(unsigned short h) {
    return __uint_as_float(((unsigned)h) << 16);
}

// ---------------------------------------------------------------------------
__device__ float g_adjS[(size_t)NB * NODE * NODE];
__device__ float g_adjF[(size_t)NB * NODE * NODE];
__device__ float g_T[(size_t)2 * NN * HID];

__device__ unsigned short g_hshi[(size_t)NN * HID], g_hslo[(size_t)NN * HID];
__device__ unsigned short g_hfhi[(size_t)NN * HID], g_hflo[(size_t)NN * HID];
__device__ unsigned short g_cshi[(size_t)NN * HID], g_cslo[(size_t)NN * HID];
__device__ unsigned short g_cfhi[(size_t)NN * HID], g_cflo[(size_t)NN * HID];
__device__ unsigned short g_t2hi[(size_t)NN * HID], g_t2lo[(size_t)NN * HID];
__device__ unsigned short g_w0thi[256 * XLD], g_w0tlo[256 * XLD];
__device__ unsigned short g_wathi[256 * 256], g_watlo[256 * 256];
__device__ unsigned short g_w1thi[256 * 512], g_w1tlo[256 * 512];

__device__ __forceinline__ float* adjPtr(int w) { return w ? g_adjF : g_adjS; }
__device__ __forceinline__ unsigned short* selhi(int w) {
    switch (w) {
        case 0: return g_hshi;
        case 1: return g_hfhi;
        case 2: return g_cshi;
        default: return g_cfhi;
    }
}
__device__ __forceinline__ unsigned short* sello(int w) {
    switch (w) {
        case 0: return g_hslo;
        case 1: return g_hflo;
        case 2: return g_cslo;
        default: return g_cflo;
    }
}
__device__ __forceinline__ unsigned short* wthi(int w) {
    switch (w) { case 0: return g_w0thi; case 1: return g_wathi; default: return g_w1thi; }
}
__device__ __forceinline__ unsigned short* wtlo(int w) {
    switch (w) { case 0: return g_w0tlo; case 1: return g_watlo; default: return g_w1tlo; }
}

// ---------------------------------------------------------------------------
// Fused adjacency with block-local dtype detection (deterministic).
// ---------------------------------------------------------------------------
__global__ __launch_bounds__(256) void k_adj_fused(const void* __restrict__ eS,
                                                   const void* __restrict__ eF) {
    __shared__ float cnt[NODE][NODE + 1];
    __shared__ float dinv[NODE];
    __shared__ int s_e64;
    int side = blockIdx.x >> 9;
    int b = blockIdx.x & 511;
    const void* edges = side ? eF : eS;
    int tid = threadIdx.x;
    const int* p32 = (const int*)edges;
    if (tid == 0) s_e64 = 1;
    for (int i = tid; i < NODE * (NODE + 1); i += 256) (&cnt[0][0])[i] = 0.f;
    __syncthreads();
    for (int i = tid; i < 1024; i += 256)
        if (p32[2 * i + 1] != 0) s_e64 = 0;
    __syncthreads();
    int e64 = s_e64;
    const long long* p64 = (const long long*)edges;
    for (int i = tid; i < 2700; i += 256) {
        int idx = b * 2700 + i;
        long long s, d;
        if (e64) { s = p64[idx]; d = p64[EDGES + idx]; }
        else     { s = p32[idx]; d = p32[EDGES + idx]; }
        int sl = (int)s - b * NODE, dl = (int)d - b * NODE;
        if (sl >= 0 && sl < NODE && dl >= 0 && dl < NODE)
            atomicAdd(&cnt[dl][sl], 1.0f);
    }
    __syncthreads();
    if (tid < NODE) {
        float s = 0.f;
        for (int k = 0; k < NODE; k++) s += cnt[tid][k];
        dinv[tid] = (s > 0.f) ? rsqrtf(s) : 0.f;
    }
    __syncthreads();
    float* adj = adjPtr(side) + (size_t)b * NODE * NODE;
    for (int i = tid; i < NODE * NODE; i += 256) {
        int d = i / NODE, s = i - d * NODE;
        adj[i] = cnt[d][s] * dinv[d] * dinv[s];
    }
}

// ---------------------------------------------------------------------------
// Weight conversions only (x converted in-GEMM now). 108 blocks.
//   [0,12): W0 ; [12,44): Wa ; [44,108): W1  (transposed hi/lo planes)
// ---------------------------------------------------------------------------
__global__ void k_conv_w(const float* __restrict__ W0, const float* __restrict__ Wa,
                         const float* __restrict__ W1) {
    int gid = blockIdx.x;
    int tid = threadIdx.x;
    const float* W;
    int K, Kpad, which, t;
    if (gid < 12)      { W = W0; K = NODE; Kpad = XLD; which = 0; t = gid * 256 + tid; }
    else if (gid < 44) { W = Wa; K = 256;  Kpad = 256; which = 1; t = (gid - 12) * 256 + tid; }
    else               { W = W1; K = 512;  Kpad = 512; which = 2; t = (gid - 44) * 256 + tid; }
    int c = t / (Kpad / 8), o = t - c * (Kpad / 8);
    unsigned short h8[8], l8[8];
#pragma unroll
    for (int j = 0; j < 8; j++) {
        int k = 8 * o + j;
        float x = (k < K) ? W[(size_t)k * 256 + c] : 0.f;
        unsigned short h = f2b(x);
        h8[j] = h;
        l8[j] = f2b(x - b2f(h));
    }
    *(uint4*)&wthi(which)[(size_t)c * Kpad + 8 * o] = *(uint4*)h8;
    *(uint4*)&wtlo(which)[(size_t)c * Kpad + 8 * o] = *(uint4*)l8;
}

// ---------------------------------------------------------------------------
// Two-sided MFMA bf16x2-split GEMM, full-width blocks (64 rows x 256 cols).
// xsel<=3: bf16 plane inputs; xsel==6: fp32 external input (xpA/xpB, row
// stride 90, K padded to 96, converted hi/lo at staging - each elem ONCE).
// emitT2=1: write hi/lo planes to g_t2* instead of fp32 g_T.
// ---------------------------------------------------------------------------
#define GK 32
#define ASTR 40
__global__ __launch_bounds__(256) void k_gemm_mfma(int xsA, int x2sA, int xsB, int x2sB,
                                                   int kld, int K, int wsel, int wld,
                                                   int emitT2, int nSide,
                                                   const float* __restrict__ xpA,
                                                   const float* __restrict__ xpB) {
    __shared__ unsigned short Ah[64][ASTR], Al[64][ASTR];
    __shared__ unsigned short Bh[256][ASTR], Bl[256][ASTR];
    int tid = threadIdx.x;
    int id = blockIdx.x;
    int side = (id >= nSide);
    int bm = side ? id - nSide : id;
    int r0 = bm * 64;
    int tbase = side ? NN : 0;
    int xsel = side ? xsB : xsA;
    int x2sel = side ? x2sB : x2sA;
    const float* xp = side ? xpB : xpA;
    int fx = (xsel >= 6);
    const unsigned short* whi_ = wthi(wsel);
    const unsigned short* wlo_ = wtlo(wsel);

    int w = tid >> 6;
    int l = tid & 63;
    int lr = l & 15;
    int lq = l >> 4;
    int koff = lq * 8;
    int sr = tid >> 2, so = (tid & 3) * 8;

    f32x4 acc[16];
#pragma unroll
    for (int c = 0; c < 16; c++) acc[c] = (f32x4){0.f, 0.f, 0.f, 0.f};

    int nt = K / GK;
    for (int t = 0; t < nt; t++) {
        int k0 = t * GK;
        __syncthreads();
        if (fx) {
            // fp32 source, convert once at staging (K real = 90)
            float xv[8];
            const float* src = xp + (size_t)(r0 + sr) * 90;
#pragma unroll
            for (int j = 0; j < 8; j++) {
                int k = k0 + so + j;
                xv[j] = (k < 90) ? src[k] : 0.f;
            }
            unsigned short h8[8], l8[8];
#pragma unroll
            for (int j = 0; j < 8; j++) {
                unsigned short h = f2b(xv[j]);
                h8[j] = h;
                l8[j] = f2b(xv[j] - b2f(h));
            }
            *(uint4*)&Ah[sr][so] = *(uint4*)h8;
            *(uint4*)&Al[sr][so] = *(uint4*)l8;
        } else {
            const unsigned short *phi, *plo;
            int xc;
            if (x2sel >= 0 && k0 >= HID) { phi = selhi(x2sel); plo = sello(x2sel); xc = k0 - HID; }
            else                          { phi = selhi(xsel);  plo = sello(xsel);  xc = k0; }
            size_t ga = (size_t)(r0 + sr) * kld + xc + so;
            *(uint4*)&Ah[sr][so] = *(const uint4*)&phi[ga];
            *(uint4*)&Al[sr][so] = *(const uint4*)&plo[ga];
        }
        {
#pragma unroll
            for (int q = 0; q < 4; q++) {
                int i = tid + (q << 8);
                int col = i >> 2, oq = (i & 3) << 3;
                size_t gb = (size_t)col * wld + k0 + oq;
                *(uint4*)&Bh[col][oq] = *(const uint4*)&whi_[gb];
                *(uint4*)&Bl[col][oq] = *(const uint4*)&wlo_[gb];
            }
        }
        __syncthreads();

        bf16x8 ah = *(const bf16x8*)&Ah[16 * w + lr][koff];
        bf16x8 al = *(const bf16x8*)&Al[16 * w + lr][koff];
#pragma unroll
        for (int c = 0; c < 16; c++) {
            bf16x8 bh = *(const bf16x8*)&Bh[16 * c + lr][koff];
            bf16x8 bl = *(const bf16x8*)&Bl[16 * c + lr][koff];
            acc[c] = __builtin_amdgcn_mfma_f32_16x16x32_bf16(ah, bh, acc[c], 0, 0, 0);
            acc[c] = __builtin_amdgcn_mfma_f32_16x16x32_bf16(ah, bl, acc[c], 0, 0, 0);
            acc[c] = __builtin_amdgcn_mfma_f32_16x16x32_bf16(al, bh, acc[c], 0, 0, 0);
        }
    }

#pragma unroll
    for (int c = 0; c < 16; c++) {
#pragma unroll
        for (int qq = 0; qq < 4; qq++) {
            size_t row = (size_t)(tbase + r0 + 16 * w + 4 * lq + qq);
            size_t col = 16 * c + lr;
            float v = acc[c][qq];
            if (emitT2) {
                unsigned short h = f2b(v);
                g_t2hi[row * HID + col] = h;
                g_t2lo[row * HID + col] = f2b(v - b2f(h));
            } else {
                g_T[row * HID + col] = v;
            }
        }
    }
}

// ---------------------------------------------------------------------------
// Fused two-stream aggregate; emits h planes + d_out copy.
// ---------------------------------------------------------------------------
__global__ __launch_bounds__(256) void k_agg2(const float* __restrict__ bias,
                                              float* __restrict__ outS,
                                              float* __restrict__ outF) {
    __shared__ float AdjT[NODE][102];
    int tid = threadIdx.x;
    int idx = blockIdx.x;
    int side = idx >> 10;
    int b = (idx & 1023) >> 1;
    int c0 = (idx & 1) * 128;
    const float* Adj = adjPtr(side) + (size_t)b * NODE * NODE;
    const float* Tg = g_T + ((size_t)side * NN + (size_t)b * NODE) * HID;
    float* outp = side ? outF : outS;
    unsigned short* phD = selhi(side);
    unsigned short* plD = sello(side);

    for (int i = tid; i < NODE * NODE; i += 256) {
        int n = i / NODE, k = i - n * NODE;
        AdjT[k][n] = Adj[i];
    }
    for (int i = tid; i < NODE * 12; i += 256) {
        int k = i / 12, n = NODE + (i % 12);
        AdjT[k][n] = 0.f;
    }
    __syncthreads();

    int ti = tid & 15, tj = tid >> 4;
    int rbase = 6 * ti;
    int cc = c0 + 8 * tj;

    float acc[6][8];
#pragma unroll
    for (int i = 0; i < 6; i++)
#pragma unroll
        for (int j = 0; j < 8; j++) acc[i][j] = 0.f;

#pragma unroll 2
    for (int k = 0; k < NODE; k++) {
        float4 t0 = *(const float4*)&Tg[(size_t)k * HID + cc];
        float4 t1 = *(const float4*)&Tg[(size_t)k * HID + cc + 4];
        float bv[8] = {t0.x, t0.y, t0.z, t0.w, t1.x, t1.y, t1.z, t1.w};
        float2 a01 = *(const float2*)&AdjT[k][rbase];
        float2 a23 = *(const float2*)&AdjT[k][rbase + 2];
        float2 a45 = *(const float2*)&AdjT[k][rbase + 4];
        float av[6] = {a01.x, a01.y, a23.x, a23.y, a45.x, a45.y};
#pragma unroll
        for (int i = 0; i < 6; i++)
#pragma unroll
            for (int j = 0; j < 8; j++)
                acc[i][j] = fmaf(av[i], bv[j], acc[i][j]);
    }

    float bb[8];
#pragma unroll
    for (int j = 0; j < 8; j++) bb[j] = bias[cc + j];

#pragma unroll
    for (int i = 0; i < 6; i++) {
        int n = rbase + i;
        if (n < NODE) {
            size_t row = (size_t)(b * NODE + n);
            float v[8];
            unsigned short h8[8], l8[8];
#pragma unroll
            for (int j = 0; j < 8; j++) {
                v[j] = fmaxf(acc[i][j] + bb[j], 0.f);
                unsigned short h = f2b(v[j]);
                h8[j] = h;
                l8[j] = f2b(v[j] - b2f(h));
            }
            *(float4*)&outp[row * 512 + cc] = make_float4(v[0], v[1], v[2], v[3]);
            *(float4*)&outp[row * 512 + cc + 4] = make_float4(v[4], v[5], v[6], v[7]);
            *(uint4*)&phD[row * HID + cc] = *(uint4*)h8;
            *(uint4*)&plD[row * HID + cc] = *(uint4*)l8;
        }
    }
}

// ---------------------------------------------------------------------------
// Fused co-attention per graph: MFMA scores (validated, col<92 guard) ->
// softmax stats (LDS) -> P in LDS -> PV phases (validated reg micro-tile,
// 64-col chunks, H reconstructed from hi/lo planes). No g_P round trip.
// LDS ~66 KB -> 2 blocks/CU. All exps bounded (tanh scores).
// ---------------------------------------------------------------------------
__global__ __launch_bounds__(256) void k_coatt(int hfsel, int hssel,
                                               float* __restrict__ outS,
                                               float* __restrict__ outF,
                                               int cssel, int cfsel, int emit) {
    __shared__ float Pm[96][92];                       // 35.3 KB
    __shared__ float rmax_[96], rinv_[96], fn_[96], gm_[96];
    __shared__ unsigned short stage[4][96][ASTR];      // 30.7 KB (aliased as Hl)
    float (*Hl)[68] = reinterpret_cast<float(*)[68]>(&stage[0][0][0]);  // 96x68x4=26.1KB

    int b = blockIdx.x;
    int tid = threadIdx.x;
    const unsigned short* t2h = g_t2hi + (size_t)b * NODE * HID;
    const unsigned short* t2l = g_t2lo + (size_t)b * NODE * HID;
    const unsigned short* hfh = selhi(hfsel) + (size_t)b * NODE * HID;
    const unsigned short* hfl_ = sello(hfsel) + (size_t)b * NODE * HID;

    // ---- phase A: At = tanh(T2 @ HF^T) via MFMA ----
    {
        int w = tid >> 6, l = tid & 63;
        int lr = l & 15, lq = l >> 4, koff = 8 * lq;
        int wr = w >> 1, wc = w & 1;

        f32x4 acc[3][3];
#pragma unroll
        for (int i = 0; i < 3; i++)
#pragma unroll
            for (int j = 0; j < 3; j++) acc[i][j] = (f32x4){0.f, 0.f, 0.f, 0.f};

        const uint4 z4 = make_uint4(0, 0, 0, 0);
        for (int t = 0; t < 8; t++) {
            int k0 = 32 * t;
            __syncthreads();
            for (int i = tid; i < 96 * 4; i += 256) {
                int r = i >> 2, o = (i & 3) << 3;
                uint4 vah = z4, val = z4, vbh = z4, vbl = z4;
                if (r < NODE) {
                    size_t g = (size_t)r * HID + k0 + o;
                    vah = *(const uint4*)&t2h[g];
                    val = *(const uint4*)&t2l[g];
                    vbh = *(const uint4*)&hfh[g];
                    vbl = *(const uint4*)&hfl_[g];
                }
                *(uint4*)&stage[0][r][o] = vah;
                *(uint4*)&stage[1][r][o] = val;
                *(uint4*)&stage[2][r][o] = vbh;
                *(uint4*)&stage[3][r][o] = vbl;
            }
            __syncthreads();

            bf16x8 ah[3], al[3], bh[3], bl[3];
#pragma unroll
            for (int i = 0; i < 3; i++) {
                ah[i] = *(const bf16x8*)&stage[0][48 * wr + 16 * i + lr][koff];
                al[i] = *(const bf16x8*)&stage[1][48 * wr + 16 * i + lr][koff];
                bh[i] = *(const bf16x8*)&stage[2][48 * wc + 16 * i + lr][koff];
                bl[i] = *(const bf16x8*)&stage[3][48 * wc + 16 * i + lr][koff];
            }
#pragma unroll
            for (int i = 0; i < 3; i++)
#pragma unroll
                for (int j = 0; j < 3; j++) {
                    acc[i][j] = __builtin_amdgcn_mfma_f32_16x16x32_bf16(ah[i], bh[j], acc[i][j], 0, 0, 0);
                    acc[i][j] = __builtin_amdgcn_mfma_f32_16x16x32_bf16(ah[i], bl[j], acc[i][j], 0, 0, 0);
                    acc[i][j] = __builtin_amdgcn_mfma_f32_16x16x32_bf16(al[i], bh[j], acc[i][j], 0, 0, 0);
                }
        }
        __syncthreads();   // all MFMA frag reads of stage done before Pm write? (Pm separate; this orders stage reuse in phase B)

#pragma unroll
        for (int i = 0; i < 3; i++)
#pragma unroll
            for (int j = 0; j < 3; j++)
#pragma unroll
                for (int qq = 0; qq < 4; qq++) {
                    int row = 48 * wr + 16 * i + 4 * lq + qq;
                    int col = 48 * wc + 16 * j + lr;
                    if (col < 92)
                        Pm[row][col] = tanh_safe(acc[i][j][qq]);
                }
    }
    __syncthreads();

    // ---- softmax stats ----
    if (tid < NODE) {
        int n = tid;
        float mx = -2.f;
        for (int m = 0; m < NODE; m++) mx = fmaxf(mx, Pm[n][m]);
        float s = 0.f;
        for (int m = 0; m < NODE; m++) s += __expf(Pm[n][m] - mx);
        rmax_[n] = mx;
        rinv_[n] = 1.f / s;
        fn_[n] = s * __expf(mx);
    } else if (tid >= 128 && tid < 128 + NODE) {
        int m = tid - 128;
        float mx = -2.f;
        for (int n = 0; n < NODE; n++) mx = fmaxf(mx, Pm[n][m]);
        float s = 0.f;
        for (int n = 0; n < NODE; n++) s += __expf(Pm[n][m] - mx);
        gm_[m] = __expf(-mx) / s;
    }
    __syncthreads();

    // ---- P = row-softmax(At) in place ----
    for (int i = tid; i < NODE * NODE; i += 256) {
        int n = i / NODE, m = i - n * NODE;
        Pm[n][m] = __expf(Pm[n][m] - rmax_[n]) * rinv_[n];
    }

    int tc = (tid & 15) << 2;    // col within 64-chunk
    int rg = tid >> 4;           // 0..15
    unsigned short* csh = selhi(cssel);
    unsigned short* csl = sello(cssel);
    unsigned short* cfh = selhi(cfsel);
    unsigned short* cfl = sello(cfsel);

    // ---- phase B: co_s = P @ HF, 4 chunks of 64 cols ----
    for (int c0 = 0; c0 < HID; c0 += 64) {
        __syncthreads();   // Pm ready (1st iter) / prev chunk compute done
        for (int i = tid; i < NODE * 8; i += 256) {
            int r = i >> 3, o = (i & 7) << 3;
            uint4 vh = *(const uint4*)&hfh[(size_t)r * HID + c0 + o];
            uint4 vl = *(const uint4*)&hfl_[(size_t)r * HID + c0 + o];
            const unsigned short* ph = (const unsigned short*)&vh;
            const unsigned short* pl = (const unsigned short*)&vl;
#pragma unroll
            for (int j = 0; j < 8; j++)
                Hl[r][o + j] = b2f(ph[j]) + b2f(pl[j]);
        }
        __syncthreads();

        float acc[6][4];
#pragma unroll
        for (int k = 0; k < 6; k++)
#pragma unroll
            for (int j = 0; j < 4; j++) acc[k][j] = 0.f;

#pragma unroll 2
        for (int m = 0; m < NODE; m++) {
            float4 h = *(const float4*)&Hl[m][tc];
#pragma unroll
            for (int k = 0; k < 6; k++) {
                int n = rg + 16 * k;
                float p = Pm[(n < NODE) ? n : 0][m];
                acc[k][0] = fmaf(p, h.x, acc[k][0]);
                acc[k][1] = fmaf(p, h.y, acc[k][1]);
                acc[k][2] = fmaf(p, h.z, acc[k][2]);
                acc[k][3] = fmaf(p, h.w, acc[k][3]);
            }
        }
#pragma unroll
        for (int k = 0; k < 6; k++) {
            int n = rg + 16 * k;
            if (n < NODE) {
                size_t row = (size_t)(b * NODE + n);
                size_t gc = c0 + tc;
                *(float4*)&outS[row * 512 + gc] =
                    make_float4(acc[k][0], acc[k][1], acc[k][2], acc[k][3]);
                if (emit) {
                    unsigned short h4[4], l4[4];
#pragma unroll
                    for (int j = 0; j < 4; j++) {
                        unsigned short h = f2b(acc[k][j]);
                        h4[j] = h;
                        l4[j] = f2b(acc[k][j] - b2f(h));
                    }
                    *(uint2*)&csh[row * HID + gc] = *(uint2*)h4;
                    *(uint2*)&csl[row * HID + gc] = *(uint2*)l4;
                }
            }
        }
    }

    // ---- phase C: co_f[m] = gm[m] * sum_n (P[n][m]*fn[n]) * HS[n] ----
    const unsigned short* hsh = selhi(hssel) + (size_t)b * NODE * HID;
    const unsigned short* hsl = sello(hssel) + (size_t)b * NODE * HID;
    for (int c0 = 0; c0 < HID; c0 += 64) {
        __syncthreads();
        for (int i = tid; i < NODE * 8; i += 256) {
            int r = i >> 3, o = (i & 7) << 3;
            uint4 vh = *(const uint4*)&hsh[(size_t)r * HID + c0 + o];
            uint4 vl = *(const uint4*)&hsl[(size_t)r * HID + c0 + o];
            const unsigned short* ph = (const unsigned short*)&vh;
            const unsigned short* pl = (const unsigned short*)&vl;
#pragma unroll
            for (int j = 0; j < 8; j++)
                Hl[r][o + j] = b2f(ph[j]) + b2f(pl[j]);
        }
        __syncthreads();

        float acc[6][4];
#pragma unroll
        for (int k = 0; k < 6; k++)
#pragma unroll
            for (int j = 0; j < 4; j++) acc[k][j] = 0.f;

#pragma unroll 2
        for (int n = 0; n < NODE; n++) {
            float4 h = *(const float4*)&Hl[n][tc];
            float f = fn_[n];
#pragma unroll
            for (int k = 0; k < 6; k++) {
                int m = rg + 16 * k;
                float p = Pm[n][(m < NODE) ? m : 0] * f;
                acc[k][0] = fmaf(p, h.x, acc[k][0]);
                acc[k][1] = fmaf(p, h.y, acc[k][1]);
                acc[k][2] = fmaf(p, h.z, acc[k][2]);
                acc[k][3] = fmaf(p, h.w, acc[k][3]);
            }
        }
#pragma unroll
        for (int k = 0; k < 6; k++) {
            int m = rg + 16 * k;
            if (m < NODE) {
                float g = gm_[m];
                size_t row = (size_t)(b * NODE + m);
                size_t gc = c0 + tc;
                float o4[4] = {acc[k][0] * g, acc[k][1] * g, acc[k][2] * g, acc[k][3] * g};
                *(float4*)&outF[row * 512 + gc] = make_float4(o4[0], o4[1], o4[2], o4[3]);
                if (emit) {
                    unsigned short h4[4], l4[4];
#pragma unroll
                    for (int j = 0; j < 4; j++) {
                        unsigned short h = f2b(o4[j]);
                        h4[j] = h;
                        l4[j] = f2b(o4[j] - b2f(h));
                    }
                    *(uint2*)&cfh[row * HID + gc] = *(uint2*)h4;
                    *(uint2*)&cfl[row * HID + gc] = *(uint2*)l4;
                }
            }
        }
    }
}

// ---------------------------------------------------------------------------
extern "C" void kernel_launch(void* const* d_in, const int* in_sizes, int n_in,
                              void* d_out, int out_size, void* d_ws, size_t ws_size,
                              hipStream_t stream) {
    const float* x_sc = (const float*)d_in[0];
    const void* e_sc = d_in[1];
    const float* x_fc = (const float*)d_in[2];
    const void* e_fc = d_in[3];
    const float* W0 = (const float*)d_in[4];
    const float* b0 = (const float*)d_in[5];
    const float* W1 = (const float*)d_in[6];
    const float* b1 = (const float*)d_in[7];
    const float* Wa = (const float*)d_in[8];

    float* out = (float*)d_out;
    size_t os = (size_t)NN * 512;
    float* x1s = out;
    float* x2s = out + os;
    float* x1f = out + 2 * os;
    float* x2f = out + 3 * os;

    const int NS = NN / 64;          // 720 row-blocks per side

    k_adj_fused<<<1024, 256, 0, stream>>>(e_sc, e_fc);
    k_conv_w<<<108, 256, 0, stream>>>(W0, Wa, W1);

    // ---- layer 1 (fp32 x converted at staging) ----
    k_gemm_mfma<<<2 * NS, 256, 0, stream>>>(6, -1, 6, -1, 90, 96, 0, XLD, 0, NS, x_sc, x_fc);
    k_agg2<<<2048, 256, 0, stream>>>(b0, x1s, x1f);

    // ---- co-attention 1 ----
    k_gemm_mfma<<<NS, 256, 0, stream>>>(0, -1, 0, -1, HID, 256, 1, 256, 1, NS, nullptr, nullptr);
    k_coatt<<<NB, 256, 0, stream>>>(1, 0, x1s + HID, x1f + HID, 2, 3, 1);

    // ---- layer 2 ----
    k_gemm_mfma<<<2 * NS, 256, 0, stream>>>(0, 2, 1, 3, HID, 512, 2, 512, 0, NS, nullptr, nullptr);
    k_agg2<<<2048, 256, 0, stream>>>(b1, x2s, x2f);

    // ---- co-attention 2 ----
    k_gemm_mfma<<<NS, 256, 0, stream>>>(0, -1, 0, -1, HID, 256, 1, 256, 1, NS, nullptr, nullptr);
    k_coatt<<<NB, 256, 0, stream>>>(1, 0, x2s + HID, x2f + HID, 2, 3, 0);
}